// Round 8
// baseline (19997.357 us; speedup 1.0000x reference)
//
#include <hip/hip_runtime.h>
#include <hip/hip_fp16.h>
#include <math.h>

// EarthMoverDistance: exact Hungarian (JV successive shortest path).
// B=8, N=1024, 3-D Euclidean cost. SSP: one wave per batch; lane owns 16
// columns (c = lane*16+k) in registers.
// R14 (base = R13, 18.95 ms; init quality plateaued at jv~19 across two
// initializers -> attack the SSP per-settle critical path):
//  - jv settle loop SOFTWARE-PIPELINED: all tie targets are known from the
//    round's ballot; issue tie t+1's row load before applying tie t, so L2
//    latency overlaps the ~180cy applyFrag instead of serializing (R13 only
//    covered the FIRST tie of each round via the cross-round runner-up
//    prefetch, which is kept). +1 in-flight Frag (~10 VGPR).
//  - auction: prefer-FREE tie columns (R11's proven tie rule, absent in
//    R13): when gm1==gm2, bid a free tied column if one exists -> breaks
//    inc=0 ping-pong stalls. AUC_ROUNDS 24->48. u-fixup unchanged => SSP
//    feasibility exact regardless.
// fp16 cost matrix in d_ws (2 MB/batch, XCD-L2 resident); FINAL SUM
// recomputed in fp32 from coords (absmax 0.0 across R6-R13 variants).

#define N     1024
#define BATCH 8
#define NSLOT 16          // columns per lane (SSP)
#define INFV  1e9f
#define AUC_ROUNDS 48

__global__ void emd_zero_kernel(float* out) { out[0] = 0.0f; }

// ---- cost cache: D[b][r][c] = fp16(dist(S1[b][r], S2[b][c])) ----
__global__ __launch_bounds__(256)
void emd_dist_kernel(const float* __restrict__ S1, const float* __restrict__ S2,
                     __half* __restrict__ D) {
    int b = blockIdx.x >> 10;
    int r = blockIdx.x & (N - 1);
    const float* s1 = S1 + ((size_t)b * N + r) * 3;
    float x1 = s1[0], y1 = s1[1], z1 = s1[2];
    const float* s2 = S2 + (size_t)b * N * 3;
    __half* drow = D + ((size_t)b * N + r) * (size_t)N;
    for (int c = threadIdx.x; c < N; c += 256) {
        float dx = x1 - s2[3 * c], dy = y1 - s2[3 * c + 1], dz = z1 - s2[3 * c + 2];
        drow[c] = __float2half_rn(sqrtf(dx * dx + dy * dy + dz * dz));
    }
}

// ---- column reduction over the fp16 matrix: v[c] = min_r C'(r,c) ----
__global__ __launch_bounds__(256)
void emd_colmin_kernel(const __half* __restrict__ D, float* __restrict__ V,
                       int* __restrict__ I) {
    int b = blockIdx.x >> 2;
    int c = ((blockIdx.x & 3) << 8) + threadIdx.x;
    const __half* Db = D + ((size_t)b << 20);
    float best = INFV; int bi = 1;
    for (int r = 0; r < N; ++r) {
        float d = __half2float(Db[(size_t)r * N + c]);
        if (d < best) { best = d; bi = r + 1; }
    }
    V[b * N + c] = best;
    I[b * N + c] = bi;
}

template<int CTRL>
__device__ __forceinline__ float dppmin(float x) {
    int xi = __float_as_int(x);
    int yi = __builtin_amdgcn_update_dpp(xi, xi, CTRL, 0xF, 0xF, false);
    return fminf(x, __int_as_float(yi));
}

__device__ __forceinline__ float wave_min_f32(float x) {
    x = dppmin<0x111>(x);   // row_shr:1
    x = dppmin<0x112>(x);   // row_shr:2
    x = dppmin<0x114>(x);   // row_shr:4
    x = dppmin<0x118>(x);   // row_shr:8
    x = dppmin<0x142>(x);   // row_bcast:15
    x = dppmin<0x143>(x);   // row_bcast:31 -> lane 63 has global min
    return __int_as_float(__builtin_amdgcn_readlane(__float_as_int(x), 63));
}

// ---- parallel auction initializer: 1024 threads (16 waves) per batch ----
// Invariants on exit (enforced by u-fixup): red(i,j)=C'(i,j)-u_i-v_j >= 0
// for all i,j (u_i = rowmin); red == 0 on every kept match.
__global__ __launch_bounds__(1024, 1)
void emd_auction_kernel(const __half* __restrict__ Dc,
                        const float* __restrict__ Vin,
                        const int* __restrict__ Iin,
                        float* __restrict__ Vw, float* __restrict__ Uw,
                        int* __restrict__ Cw, int* __restrict__ Rw) {
    __shared__ float v0[N];                 // column potentials, 0-indexed
    __shared__ int   rowm[N + 1];           // row -> col (1-idx), 0 = free
    __shared__ int   colm[N + 1];           // col -> row (1-idx), 0 = free
    __shared__ unsigned long long bid[N + 1];
    __shared__ int   qbuf[N];
    __shared__ int   qn;

    const int tid  = threadIdx.x;
    const int lane = tid & 63;
    const int wv   = tid >> 6;              // wave id 0..15
    const int b    = blockIdx.x;
    const __half* Db = Dc + ((size_t)b << 20);

    for (int t = tid; t <= N; t += 1024) { rowm[t] = 0; colm[t] = 0; bid[t] = 0ull; }
    for (int c = tid; c < N; c += 1024) v0[c] = Vin[b * N + c];
    __syncthreads();

    // greedy on tight edges (column -> its argmin row from colmin kernel)
    for (int c = tid; c < N; c += 1024) {
        int r = Iin[b * N + c];             // 1-indexed row
        int old = atomicCAS(&rowm[r], 0, c + 1);
        if (old == 0) colm[c + 1] = r;
    }
    __syncthreads();

    // per-wave row scan: red[k] = C'(i, lane*16+k) - v0[...]
    auto rowRed16 = [&](int i, float (&red)[16]) {
        const uint4* dr = (const uint4*)(Db + (size_t)(i - 1) * N);
        uint4 w0 = dr[lane * 2 + 0];
        uint4 w1 = dr[lane * 2 + 1];
        unsigned wb[8] = { w0.x, w0.y, w0.z, w0.w, w1.x, w1.y, w1.z, w1.w };
        const float4* vp = (const float4*)(v0 + lane * 16);   // 64B aligned
        float4 vv0 = vp[0], vv1 = vp[1], vv2 = vp[2], vv3 = vp[3];
        float vv[16] = { vv0.x, vv0.y, vv0.z, vv0.w, vv1.x, vv1.y, vv1.z, vv1.w,
                         vv2.x, vv2.y, vv2.z, vv2.w, vv3.x, vv3.y, vv3.z, vv3.w };
#pragma unroll
        for (int t = 0; t < 8; ++t) {
            __half2 hh = *reinterpret_cast<const __half2*>(&wb[t]);
            float2 f2 = __half22float2(hh);
            red[2 * t]     = f2.x - vv[2 * t];
            red[2 * t + 1] = f2.y - vv[2 * t + 1];
        }
    };

    // ---- bidding rounds ----
    for (int round = 0; round < AUC_ROUNDS; ++round) {
        if (tid == 0) qn = 0;
        __syncthreads();
        for (int i = tid + 1; i <= N; i += 1024)
            if (rowm[i] == 0) { int p = atomicAdd(&qn, 1); qbuf[p] = i; }
        __syncthreads();
        int nq = qn;
        if (nq == 0) break;

        for (int q = wv; q < nq; q += 16) {
            int i = qbuf[q];
            float red[16];
            rowRed16(i, red);
            // local (min, secmin, argmin-col 0-idx): 4 chains of depth 4
            float a1 = INFV, a2 = INFV; int ac = 0;
            float e1 = INFV, e2 = INFV; int ec = 0;
            float f1 = INFV, f2 = INFV; int fc = 0;
            float g1 = INFV, g2 = INFV; int gc = 0;
#pragma unroll
            for (int k = 0; k < 4; ++k) {
                float u0 = red[k];
                bool t0 = u0 < a1;
                a2 = t0 ? a1 : (u0 < a2 ? u0 : a2);
                ac = t0 ? (lane * 16 + k) : ac;  a1 = t0 ? u0 : a1;
                float u1 = red[k + 4];
                bool t1 = u1 < e1;
                e2 = t1 ? e1 : (u1 < e2 ? u1 : e2);
                ec = t1 ? (lane * 16 + k + 4) : ec;  e1 = t1 ? u1 : e1;
                float u2 = red[k + 8];
                bool t2 = u2 < f1;
                f2 = t2 ? f1 : (u2 < f2 ? u2 : f2);
                fc = t2 ? (lane * 16 + k + 8) : fc;  f1 = t2 ? u2 : f1;
                float u3 = red[k + 12];
                bool t3 = u3 < g1;
                g2 = t3 ? g1 : (u3 < g2 ? u3 : g2);
                gc = t3 ? (lane * 16 + k + 12) : gc;  g1 = t3 ? u3 : g1;
            }
            bool sae = e1 < a1;
            float ae1 = sae ? e1 : a1; int aec = sae ? ec : ac;
            float ae2 = fminf(fminf(a2, e2), sae ? a1 : e1);
            bool sfg = g1 < f1;
            float fg1 = sfg ? g1 : f1; int fgc = sfg ? gc : fc;
            float fg2 = fminf(fminf(f2, g2), sfg ? f1 : g1);
            bool sall = fg1 < ae1;
            float m1 = sall ? fg1 : ae1;
            int   c1 = sall ? fgc : aec;
            float m2 = fminf(fminf(ae2, fg2), sall ? ae1 : fg1);

            // wave argmin with payload (uniform results on all lanes)
            float gm1 = wave_min_f32(m1);
            unsigned long long wbm = __ballot(m1 == gm1);
            int wl = __ffsll((long long)wbm) - 1;
            float cand2 = (lane == wl) ? m2 : m1;
            float gm2 = wave_min_f32(cand2);
            int gcol;
            if (gm1 < gm2) {
                gcol = __builtin_amdgcn_readlane(c1, wl);   // unique argmin
            } else {
                // ties: prefer a FREE tied column (R11's rule; breaks
                // inc=0 ping-pong). Few ties/lane -> few LDS reads.
                unsigned tmask = 0u;
#pragma unroll
                for (int k = 0; k < 16; ++k)
                    tmask |= (red[k] == gm1) ? (1u << k) : 0u;
                unsigned fmask = 0u;
                unsigned tt = tmask;
                while (tt) {
                    int k = __ffs((int)tt) - 1;
                    tt &= tt - 1;
                    if (colm[lane * 16 + k + 1] == 0) fmask |= (1u << k);
                }
                unsigned long long bf = __ballot(fmask != 0u);
                if (bf != 0ull) {
                    int l = __ffsll((long long)bf) - 1;
                    unsigned mk = (unsigned)__builtin_amdgcn_readlane((int)fmask, l);
                    gcol = l * 16 + (__ffs((int)mk) - 1);
                } else {
                    gcol = __builtin_amdgcn_readlane(c1, wl);  // lowest tied
                }
            }
            float inc = gm2 - gm1;                          // >= 0

            if (lane == 0) {
                unsigned long long key =
                    ((unsigned long long)__float_as_uint(inc) << 32) |
                    (unsigned long long)(unsigned)i;
                atomicMax(&bid[gcol + 1], key);
            }
        }
        __syncthreads();

        // acceptance: column j takes its best bid; displaced row freed
        for (int j = tid + 1; j <= N; j += 1024) {
            unsigned long long bb = bid[j];
            if (bb != 0ull) {
                bid[j] = 0ull;
                int i = (int)(unsigned)(bb & 0xFFFFFFFFull);
                float inc = __uint_as_float((unsigned)(bb >> 32));
                int old = colm[j];
                colm[j] = i;
                rowm[i] = j;
                if (old) rowm[old] = 0;
                v0[j - 1] -= inc;
            }
        }
        __syncthreads();
    }

    // ---- u-fixup: u_i = rowmin(red_i) for all rows; drop non-tight ----
    for (int q = wv; q < N; q += 16) {
        int i = q + 1;
        float red[16];
        rowRed16(i, red);
        int j = rowm[i];                    // wave-uniform (LDS broadcast)
        // extract red at matched col before destroying red[]
        float rloc = red[0];
        int lo = 0, kk = 0;
        if (j) {
            lo = (j - 1) >> 4; kk = (j - 1) & 15;
#pragma unroll
            for (int k = 1; k < 16; ++k) if (k == kk) rloc = red[k];
        }
        // destructive tree min
#pragma unroll
        for (int s = 1; s < 16; s <<= 1) {
#pragma unroll
            for (int k = 0; k < 16; k += 2 * s)
                red[k] = fminf(red[k], red[k + s]);
        }
        float m = wave_min_f32(red[0]);
        if (j) {
            float rm = __int_as_float(
                __builtin_amdgcn_readlane(__float_as_int(rloc), lo));
            if (lane == 0 && rm != m) { rowm[i] = 0; colm[j] = 0; }
        }
        if (lane == 0) Uw[b * N + q] = m;
    }
    __syncthreads();

    // ---- write state for the SSP kernel ----
    for (int c = tid; c < N; c += 1024) {
        Vw[b * N + c] = v0[c];
        Cw[b * N + c] = colm[c + 1];
    }
    for (int t = tid; t < N; t += 1024) Rw[b * N + t] = rowm[t + 1];
}

struct Frag { uint4 w0, w1; float ur; float4 q; };

template<bool CACHED, bool PRE>
__global__ __launch_bounds__(64, 1)
void emd_jv_kernel(const float* __restrict__ S1,
                   const float* __restrict__ S2,
                   const __half* __restrict__ Dc,
                   const float* __restrict__ Vin,
                   const int*   __restrict__ Iin,
                   const float* __restrict__ Uw,
                   const int*   __restrict__ Cw,
                   const int*   __restrict__ Rw,
                   float* __restrict__ out) {
    __shared__ float4 s1u[N + 1];     // row coords (both modes; final fp32 sum)
    __shared__ float  u_lds[N + 1];   // row potentials
    __shared__ float  dentry[N + 1];  // D value when column settled
    __shared__ int    rowm[N + 1];    // row -> matched col (0 = free)

    const int lane = threadIdx.x;
    const int b = blockIdx.x;
    const float* s1g = S1 + (size_t)b * N * 3;
    const float* s2g = S2 + (size_t)b * N * 3;
    const __half* Db = CACHED ? (Dc + ((size_t)b << 20)) : (const __half*)0;
    const float NANF = __int_as_float(0x7fc00000);

    for (int t = lane; t < N; t += 64) {
        s1u[t + 1] = make_float4(s1g[3 * t], s1g[3 * t + 1], s1g[3 * t + 2], 0.0f);
        u_lds[t + 1] = PRE ? Uw[b * N + t] : 0.0f;
        rowm[t + 1] = PRE ? Rw[b * N + t] : 0;
    }
    if (lane == 0) { u_lds[0] = 0.0f; rowm[0] = 0; }

    // ---- per-lane column state: col j = c+1, c = lane*16+k ----
    float v[NSLOT];       // column potentials
    int   pr[NSLOT];      // matched row (0 = free)
    int   jpk[NSLOT];     // packed (pr<<11)|j
    float x2[NSLOT], y2[NSLOT], z2[NSLOT];  // S2 coords (final fp32 sum)

#pragma unroll
    for (int k = 0; k < NSLOT; ++k) {
        int pt = lane * NSLOT + k;
        x2[k] = s2g[3 * pt + 0];
        y2[k] = s2g[3 * pt + 1];
        z2[k] = s2g[3 * pt + 2];
    }

    if constexpr (PRE) {
#pragma unroll
        for (int k = 0; k < NSLOT; ++k) {
            int c = lane * NSLOT + k;
            v[k] = Vin[b * N + c];        // Vin = auction-updated v
            pr[k] = Cw[b * N + c];
            jpk[k] = (pr[k] << 11) | (c + 1);
        }
        __syncthreads();
    } else {
        int imin[NSLOT];
        if constexpr (CACHED) {
#pragma unroll
            for (int k = 0; k < NSLOT; ++k) {
                int c = lane * NSLOT + k;
                v[k] = Vin[b * N + c];
                imin[k] = Iin[b * N + c];
            }
        } else {
#pragma unroll
            for (int k = 0; k < NSLOT; ++k) { v[k] = INFV; imin[k] = 1; }
        }
        __syncthreads();

        if constexpr (!CACHED) {
            for (int r = 1; r <= N; ++r) {
                float4 qq = s1u[r];
#pragma unroll
                for (int k = 0; k < NSLOT; ++k) {
                    float dx = qq.x - x2[k], dy = qq.y - y2[k], dz = qq.z - z2[k];
                    float d2 = dx * dx + dy * dy + dz * dz;
                    bool upd = d2 < v[k];
                    v[k] = upd ? d2 : v[k];
                    imin[k] = upd ? r : imin[k];
                }
            }
#pragma unroll
            for (int k = 0; k < NSLOT; ++k) v[k] = sqrtf(v[k]);
        }

        // greedy matching on tight edges
#pragma unroll
        for (int k = 0; k < NSLOT; ++k) {
            int j = lane * NSLOT + k + 1;
            int r = imin[k];
            int old = atomicCAS(&rowm[r], 0, j);
            pr[k] = (old == 0) ? r : 0;
            jpk[k] = (pr[k] << 11) | j;
        }
        __syncthreads();
    }

    float minv[NSLOT];
    int   way[NSLOT];

    // issue row-r loads (cost-row fragment + u[r]); consumer waits only these
    auto issueLoads = [&](int rr) -> Frag {
        Frag F;
        if (CACHED) {
            const uint4* dr = (const uint4*)(Db + (size_t)(rr - 1) * N);
            F.w0 = dr[lane * 2 + 0];       // 8 halves
            F.w1 = dr[lane * 2 + 1];       // 8 halves
        } else {
            F.q = s1u[rr];
        }
        F.ur = u_lds[rr];
        return F;
    };

    auto applyFrag = [&](const Frag& F, int jpred, float Dh) {
        float base = Dh - F.ur;
        if (CACHED) {
            float h[NSLOT];
            const unsigned* w = (const unsigned*)&F.w0;   // w0,w1 contiguous
#pragma unroll
            for (int t = 0; t < 8; ++t) {
                unsigned word = w[t];
                __half2 hh = *reinterpret_cast<const __half2*>(&word);
                float2 f2 = __half22float2(hh);
                h[2 * t] = f2.x; h[2 * t + 1] = f2.y;
            }
#pragma unroll
            for (int k = 0; k < NSLOT; ++k) {
                float cur = (h[k] - v[k]) + base;
                bool upd = cur < minv[k];         // false for NaN (settled)
                minv[k] = upd ? cur : minv[k];
                way[k] = upd ? jpred : way[k];
            }
        } else {
#pragma unroll
            for (int k = 0; k < NSLOT; ++k) {
                float dx = F.q.x - x2[k], dy = F.q.y - y2[k], dz = F.q.z - z2[k];
                float d = sqrtf(dx * dx + dy * dy + dz * dz);
                float cur = (d - v[k]) + base;
                bool upd = cur < minv[k];
                minv[k] = upd ? cur : minv[k];
                way[k] = upd ? jpred : way[k];
            }
        }
    };

    // ---- successive shortest paths for free rows (exact on C') ----
    for (int i = 1; i <= N; ++i) {
        if (rowm[i] != 0) continue;

        unsigned used = 0u;
        float DT = 0.0f;
        int freecol = 0;
        int pred = 0;      // speculative prefetch: predicted next winner row
        Frag P;            // only read when pred != 0 (assigned then)

        Frag F0 = issueLoads(i);          // overlaps minv/way init
#pragma unroll
        for (int k = 0; k < NSLOT; ++k) { minv[k] = INFV; way[k] = 0; }
        applyFrag(F0, 0, 0.0f);

        int guard = 0;
        for (;;) {
            if (++guard > N + 4) break;
            // local argmin: 4 independent depth-4 chains + 2-level merge.
            float b0 = INFV, b1 = INFV, b2 = INFV, b3 = INFV;
            int   p0 = 0, p1 = 0, p2 = 0, p3 = 0;
#pragma unroll
            for (int k = 0; k < 4; ++k) {
                bool t0 = minv[k]      < b0;
                b0 = t0 ? minv[k]      : b0;  p0 = t0 ? jpk[k]      : p0;
                bool t1 = minv[k + 4]  < b1;
                b1 = t1 ? minv[k + 4]  : b1;  p1 = t1 ? jpk[k + 4]  : p1;
                bool t2 = minv[k + 8]  < b2;
                b2 = t2 ? minv[k + 8]  : b2;  p2 = t2 ? jpk[k + 8]  : p2;
                bool t3 = minv[k + 12] < b3;
                b3 = t3 ? minv[k + 12] : b3;  p3 = t3 ? jpk[k + 12] : p3;
            }
            bool m01 = b1 < b0;  float ba = m01 ? b1 : b0;  int pa = m01 ? p1 : p0;
            bool m23 = b3 < b2;  float bb = m23 ? b3 : b2;  int pb = m23 ? p3 : p2;
            bool mab = bb < ba;  float bestv = mab ? bb : ba;
            int bestjp = mab ? pb : pa;

            float gmin = wave_min_f32(bestv);
            if (!(gmin < INFV * 0.5f)) break;
            unsigned long long tm = __ballot(bestv == gmin);
            DT = gmin;
            freecol = 0;

            // 1) free-column short-circuit: zero expands if any tie is free
            {
                unsigned long long tf = tm;
                while (tf) {
                    int l = __ffsll((long long)tf) - 1;
                    tf &= tf - 1;
                    int jp = __builtin_amdgcn_readlane(bestjp, l);
                    if ((jp >> 11) == 0) { freecol = jp & 0x7FF; break; }
                }
            }
            if (freecol) break;

            // 2) settle all matched ties at gmin — software-pipelined:
            //    issue tie t+1's load before applying tie t.
            {
                int l0 = __ffsll((long long)tm) - 1;
                tm &= tm - 1;
                int jp_cur = __builtin_amdgcn_readlane(bestjp, l0);
                int rr0 = jp_cur >> 11;
                Frag Fcur;
                if (CACHED && pred != 0 && rr0 == pred) {
                    Fcur = P;                      // prefetch hit
                } else {
                    Fcur = issueLoads(rr0);
                }
                if (CACHED) {
                    // cross-round runner-up prefetch; the wave-min + ballot
                    // here hide under Fcur's L2 latency. (u_lds constant
                    // during a search -> P stays valid even if its row is
                    // settled this round.)
                    float ru = (bestv == gmin) ? INFV : bestv;
                    float rmin = wave_min_f32(ru);
                    pred = 0;
                    if (rmin < INFV * 0.5f) {
                        unsigned long long rb = __ballot(ru == rmin);
                        int rl = __ffsll((long long)rb) - 1;
                        int rjp = __builtin_amdgcn_readlane(bestjp, rl);
                        int prr = rjp >> 11;
                        if (prr != 0) { pred = prr; P = issueLoads(prr); }
                    }
                }
                for (;;) {
                    int jp_nxt = 0;
                    Frag Fnxt;
                    if (tm) {
                        int l = __ffsll((long long)tm) - 1;
                        tm &= tm - 1;
                        jp_nxt = __builtin_amdgcn_readlane(bestjp, l);
                        Fnxt = issueLoads(jp_nxt >> 11);   // flies during apply
                    }
                    int jj = jp_cur & 0x7FF;
                    if (lane == 0) dentry[jj] = gmin;
                    int cc = jj - 1, lo = cc >> 4, kk = cc & 15;
                    bool mine = (lane == lo);
#pragma unroll
                    for (int k = 0; k < NSLOT; ++k)
                        if (k == kk && mine) { minv[k] = NANF; used |= (1u << k); }
                    applyFrag(Fcur, jj, gmin);
                    if (!jp_nxt) break;
                    jp_cur = jp_nxt;
                    Fcur = Fnxt;
                }
            }
        }
        if (freecol == 0) continue;

        // deferred dual updates (pre-augment pr)
        if (lane == 0) u_lds[i] += DT;
#pragma unroll
        for (int k = 0; k < NSLOT; ++k) {
            if ((used >> k) & 1u) {
                int j = lane * NSLOT + k + 1;
                float dd = DT - dentry[j];
                v[k] -= dd;
                u_lds[pr[k]] += dd;      // distinct rows: race-free
            }
        }
        __syncthreads();

        // augment along alternating path (register p via readlanes)
        int j0 = freecol;
        int aguard = 0;
        while (j0 != 0) {
            if (++aguard > N + 4) break;
            int cc = j0 - 1;
            int lo = cc >> 4, kk = cc & 15;
            int wloc = way[0];
#pragma unroll
            for (int k = 1; k < NSLOT; ++k) if (k == kk) wloc = way[k];
            int j1 = __builtin_amdgcn_readlane(wloc, lo);
            int np;
            if (j1 == 0) np = i;
            else {
                int c1 = j1 - 1;
                int lo1 = c1 >> 4, kk1 = c1 & 15;
                int ploc = pr[0];
#pragma unroll
                for (int k = 1; k < NSLOT; ++k) if (k == kk1) ploc = pr[k];
                np = __builtin_amdgcn_readlane(ploc, lo1);
            }
            bool mine = (lane == lo);
#pragma unroll
            for (int k = 0; k < NSLOT; ++k)
                if (k == kk) {
                    if (mine) { pr[k] = np; jpk[k] = (np << 11) | j0; }
                }
            if (lane == 0) rowm[np] = j0;
            j0 = j1;
        }
        __syncthreads();
    }

    // ---- total matched cost: exact fp32 from coordinates ----
    float sum = 0.0f;
#pragma unroll
    for (int k = 0; k < NSLOT; ++k) {
        int r = pr[k] > 0 ? pr[k] : 1;
        float4 qq = s1u[r];
        float dx = qq.x - x2[k], dy = qq.y - y2[k], dz = qq.z - z2[k];
        sum += sqrtf(dx * dx + dy * dy + dz * dz);
    }
#pragma unroll
    for (int off = 32; off >= 1; off >>= 1) sum += __shfl_xor(sum, off);
    if (lane == 0) atomicAdd(out, sum * (1.0f / ((float)N * (float)BATCH)));
}

extern "C" void kernel_launch(void* const* d_in, const int* in_sizes, int n_in,
                              void* d_out, int out_size, void* d_ws, size_t ws_size,
                              hipStream_t stream) {
    const float* S1 = (const float*)d_in[0];
    const float* S2 = (const float*)d_in[1];
    float* out = (float*)d_out;

    size_t needD  = (size_t)BATCH * N * N * sizeof(__half);
    size_t vecB   = (size_t)BATCH * N * 4;            // one per-col/per-row array
    size_t needT  = needD + 2 * vecB;                 // V + I            (R8 tier)
    size_t needT2 = needD + 6 * vecB;                 // + Vw,Uw,Cw,Rw    (R13 tier)

    emd_zero_kernel<<<1, 1, 0, stream>>>(out);

    if (ws_size >= needT2) {
        __half* D  = (__half*)d_ws;
        float*  V  = (float*)((char*)d_ws + needD);
        int*    I  = (int*)((char*)V + vecB);
        float*  Vw = (float*)((char*)I + vecB);
        float*  Uw = (float*)((char*)Vw + vecB);
        int*    Cw = (int*)((char*)Uw + vecB);
        int*    Rw = (int*)((char*)Cw + vecB);
        emd_dist_kernel<<<BATCH * N, 256, 0, stream>>>(S1, S2, D);
        emd_colmin_kernel<<<BATCH * 4, 256, 0, stream>>>(D, V, I);
        emd_auction_kernel<<<BATCH, 1024, 0, stream>>>(D, V, I, Vw, Uw, Cw, Rw);
        emd_jv_kernel<true, true><<<BATCH, 64, 0, stream>>>(
            S1, S2, D, Vw, nullptr, Uw, Cw, Rw, out);
    } else if (ws_size >= needT) {
        __half* D = (__half*)d_ws;
        float*  V = (float*)((char*)d_ws + needD);
        int*    I = (int*)((char*)V + vecB);
        emd_dist_kernel<<<BATCH * N, 256, 0, stream>>>(S1, S2, D);
        emd_colmin_kernel<<<BATCH * 4, 256, 0, stream>>>(D, V, I);
        emd_jv_kernel<true, false><<<BATCH, 64, 0, stream>>>(
            S1, S2, D, V, I, nullptr, nullptr, nullptr, out);
    } else {
        emd_jv_kernel<false, false><<<BATCH, 64, 0, stream>>>(
            S1, S2, nullptr, nullptr, nullptr, nullptr, nullptr, nullptr, out);
    }
}

// Round 9
// 17807.144 us; speedup vs baseline: 1.1230x; 1.1230x over previous
//
#include <hip/hip_runtime.h>
#include <hip/hip_fp16.h>
#include <math.h>

// EarthMoverDistance: exact Hungarian (JV successive shortest path).
// B=8, N=1024, 3-D Euclidean cost. SSP: one wave per batch; lane owns 16
// columns (c = lane*16+k) in registers.
// R15 (attribution round; base = R13, 18.95 ms):
//  - R14 bundled {jv settle-pipeline + auction prefer-free/48-rounds} and
//    regressed to 20.0 ms with jv VALUBusy 0.27->0.24 (more stall/round)
//    => prime suspect is the jv pipeline (Frag copies + control flow on the
//    single-tie common path). This round: jv reverted BYTE-IDENTICAL to
//    R13; ONLY the auction changes kept (prefer-FREE tie columns, R11's
//    rule, breaks inc=0 ping-pong; AUC_ROUNDS 48). Tie-matches are tight
//    (red == rowmin) so u-fixup keeps them; SSP exactness unchanged.
//  - Expected: fewer free rows after auction -> fewer SSP searches.
//    jv <= 19.0 => auction change fine, R14 regression = jv pipeline.
//    jv ~ 20   => auction change is the culprit; full R13 revert next.
// fp16 cost matrix in d_ws (2 MB/batch, XCD-L2 resident); FINAL SUM
// recomputed in fp32 from coords (absmax 0.0 across R6-R14 variants).

#define N     1024
#define BATCH 8
#define NSLOT 16          // columns per lane (SSP)
#define INFV  1e9f
#define AUC_ROUNDS 48

__global__ void emd_zero_kernel(float* out) { out[0] = 0.0f; }

// ---- cost cache: D[b][r][c] = fp16(dist(S1[b][r], S2[b][c])) ----
__global__ __launch_bounds__(256)
void emd_dist_kernel(const float* __restrict__ S1, const float* __restrict__ S2,
                     __half* __restrict__ D) {
    int b = blockIdx.x >> 10;
    int r = blockIdx.x & (N - 1);
    const float* s1 = S1 + ((size_t)b * N + r) * 3;
    float x1 = s1[0], y1 = s1[1], z1 = s1[2];
    const float* s2 = S2 + (size_t)b * N * 3;
    __half* drow = D + ((size_t)b * N + r) * (size_t)N;
    for (int c = threadIdx.x; c < N; c += 256) {
        float dx = x1 - s2[3 * c], dy = y1 - s2[3 * c + 1], dz = z1 - s2[3 * c + 2];
        drow[c] = __float2half_rn(sqrtf(dx * dx + dy * dy + dz * dz));
    }
}

// ---- column reduction over the fp16 matrix: v[c] = min_r C'(r,c) ----
__global__ __launch_bounds__(256)
void emd_colmin_kernel(const __half* __restrict__ D, float* __restrict__ V,
                       int* __restrict__ I) {
    int b = blockIdx.x >> 2;
    int c = ((blockIdx.x & 3) << 8) + threadIdx.x;
    const __half* Db = D + ((size_t)b << 20);
    float best = INFV; int bi = 1;
    for (int r = 0; r < N; ++r) {
        float d = __half2float(Db[(size_t)r * N + c]);
        if (d < best) { best = d; bi = r + 1; }
    }
    V[b * N + c] = best;
    I[b * N + c] = bi;
}

template<int CTRL>
__device__ __forceinline__ float dppmin(float x) {
    int xi = __float_as_int(x);
    int yi = __builtin_amdgcn_update_dpp(xi, xi, CTRL, 0xF, 0xF, false);
    return fminf(x, __int_as_float(yi));
}

__device__ __forceinline__ float wave_min_f32(float x) {
    x = dppmin<0x111>(x);   // row_shr:1
    x = dppmin<0x112>(x);   // row_shr:2
    x = dppmin<0x114>(x);   // row_shr:4
    x = dppmin<0x118>(x);   // row_shr:8
    x = dppmin<0x142>(x);   // row_bcast:15
    x = dppmin<0x143>(x);   // row_bcast:31 -> lane 63 has global min
    return __int_as_float(__builtin_amdgcn_readlane(__float_as_int(x), 63));
}

// ---- parallel auction initializer: 1024 threads (16 waves) per batch ----
// Invariants on exit (enforced by u-fixup): red(i,j)=C'(i,j)-u_i-v_j >= 0
// for all i,j (u_i = rowmin); red == 0 on every kept match.
__global__ __launch_bounds__(1024, 1)
void emd_auction_kernel(const __half* __restrict__ Dc,
                        const float* __restrict__ Vin,
                        const int* __restrict__ Iin,
                        float* __restrict__ Vw, float* __restrict__ Uw,
                        int* __restrict__ Cw, int* __restrict__ Rw) {
    __shared__ float v0[N];                 // column potentials, 0-indexed
    __shared__ int   rowm[N + 1];           // row -> col (1-idx), 0 = free
    __shared__ int   colm[N + 1];           // col -> row (1-idx), 0 = free
    __shared__ unsigned long long bid[N + 1];
    __shared__ int   qbuf[N];
    __shared__ int   qn;

    const int tid  = threadIdx.x;
    const int lane = tid & 63;
    const int wv   = tid >> 6;              // wave id 0..15
    const int b    = blockIdx.x;
    const __half* Db = Dc + ((size_t)b << 20);

    for (int t = tid; t <= N; t += 1024) { rowm[t] = 0; colm[t] = 0; bid[t] = 0ull; }
    for (int c = tid; c < N; c += 1024) v0[c] = Vin[b * N + c];
    __syncthreads();

    // greedy on tight edges (column -> its argmin row from colmin kernel)
    for (int c = tid; c < N; c += 1024) {
        int r = Iin[b * N + c];             // 1-indexed row
        int old = atomicCAS(&rowm[r], 0, c + 1);
        if (old == 0) colm[c + 1] = r;
    }
    __syncthreads();

    // per-wave row scan: red[k] = C'(i, lane*16+k) - v0[...]
    auto rowRed16 = [&](int i, float (&red)[16]) {
        const uint4* dr = (const uint4*)(Db + (size_t)(i - 1) * N);
        uint4 w0 = dr[lane * 2 + 0];
        uint4 w1 = dr[lane * 2 + 1];
        unsigned wb[8] = { w0.x, w0.y, w0.z, w0.w, w1.x, w1.y, w1.z, w1.w };
        const float4* vp = (const float4*)(v0 + lane * 16);   // 64B aligned
        float4 vv0 = vp[0], vv1 = vp[1], vv2 = vp[2], vv3 = vp[3];
        float vv[16] = { vv0.x, vv0.y, vv0.z, vv0.w, vv1.x, vv1.y, vv1.z, vv1.w,
                         vv2.x, vv2.y, vv2.z, vv2.w, vv3.x, vv3.y, vv3.z, vv3.w };
#pragma unroll
        for (int t = 0; t < 8; ++t) {
            __half2 hh = *reinterpret_cast<const __half2*>(&wb[t]);
            float2 f2 = __half22float2(hh);
            red[2 * t]     = f2.x - vv[2 * t];
            red[2 * t + 1] = f2.y - vv[2 * t + 1];
        }
    };

    // ---- bidding rounds ----
    for (int round = 0; round < AUC_ROUNDS; ++round) {
        if (tid == 0) qn = 0;
        __syncthreads();
        for (int i = tid + 1; i <= N; i += 1024)
            if (rowm[i] == 0) { int p = atomicAdd(&qn, 1); qbuf[p] = i; }
        __syncthreads();
        int nq = qn;
        if (nq == 0) break;

        for (int q = wv; q < nq; q += 16) {
            int i = qbuf[q];
            float red[16];
            rowRed16(i, red);
            // local (min, secmin, argmin-col 0-idx): 4 chains of depth 4
            float a1 = INFV, a2 = INFV; int ac = 0;
            float e1 = INFV, e2 = INFV; int ec = 0;
            float f1 = INFV, f2 = INFV; int fc = 0;
            float g1 = INFV, g2 = INFV; int gc = 0;
#pragma unroll
            for (int k = 0; k < 4; ++k) {
                float u0 = red[k];
                bool t0 = u0 < a1;
                a2 = t0 ? a1 : (u0 < a2 ? u0 : a2);
                ac = t0 ? (lane * 16 + k) : ac;  a1 = t0 ? u0 : a1;
                float u1 = red[k + 4];
                bool t1 = u1 < e1;
                e2 = t1 ? e1 : (u1 < e2 ? u1 : e2);
                ec = t1 ? (lane * 16 + k + 4) : ec;  e1 = t1 ? u1 : e1;
                float u2 = red[k + 8];
                bool t2 = u2 < f1;
                f2 = t2 ? f1 : (u2 < f2 ? u2 : f2);
                fc = t2 ? (lane * 16 + k + 8) : fc;  f1 = t2 ? u2 : f1;
                float u3 = red[k + 12];
                bool t3 = u3 < g1;
                g2 = t3 ? g1 : (u3 < g2 ? u3 : g2);
                gc = t3 ? (lane * 16 + k + 12) : gc;  g1 = t3 ? u3 : g1;
            }
            bool sae = e1 < a1;
            float ae1 = sae ? e1 : a1; int aec = sae ? ec : ac;
            float ae2 = fminf(fminf(a2, e2), sae ? a1 : e1);
            bool sfg = g1 < f1;
            float fg1 = sfg ? g1 : f1; int fgc = sfg ? gc : fc;
            float fg2 = fminf(fminf(f2, g2), sfg ? f1 : g1);
            bool sall = fg1 < ae1;
            float m1 = sall ? fg1 : ae1;
            int   c1 = sall ? fgc : aec;
            float m2 = fminf(fminf(ae2, fg2), sall ? ae1 : fg1);

            // wave argmin with payload (uniform results on all lanes)
            float gm1 = wave_min_f32(m1);
            unsigned long long wbm = __ballot(m1 == gm1);
            int wl = __ffsll((long long)wbm) - 1;
            float cand2 = (lane == wl) ? m2 : m1;
            float gm2 = wave_min_f32(cand2);
            int gcol;
            if (gm1 < gm2) {
                gcol = __builtin_amdgcn_readlane(c1, wl);   // unique argmin
            } else {
                // ties: prefer a FREE tied column (R11's rule; breaks
                // inc=0 ping-pong). Few ties/lane -> few LDS reads.
                unsigned tmask = 0u;
#pragma unroll
                for (int k = 0; k < 16; ++k)
                    tmask |= (red[k] == gm1) ? (1u << k) : 0u;
                unsigned fmask = 0u;
                unsigned tt = tmask;
                while (tt) {
                    int k = __ffs((int)tt) - 1;
                    tt &= tt - 1;
                    if (colm[lane * 16 + k + 1] == 0) fmask |= (1u << k);
                }
                unsigned long long bf = __ballot(fmask != 0u);
                if (bf != 0ull) {
                    int l = __ffsll((long long)bf) - 1;
                    unsigned mk = (unsigned)__builtin_amdgcn_readlane((int)fmask, l);
                    gcol = l * 16 + (__ffs((int)mk) - 1);
                } else {
                    gcol = __builtin_amdgcn_readlane(c1, wl);  // lowest tied
                }
            }
            float inc = gm2 - gm1;                          // >= 0

            if (lane == 0) {
                unsigned long long key =
                    ((unsigned long long)__float_as_uint(inc) << 32) |
                    (unsigned long long)(unsigned)i;
                atomicMax(&bid[gcol + 1], key);
            }
        }
        __syncthreads();

        // acceptance: column j takes its best bid; displaced row freed
        for (int j = tid + 1; j <= N; j += 1024) {
            unsigned long long bb = bid[j];
            if (bb != 0ull) {
                bid[j] = 0ull;
                int i = (int)(unsigned)(bb & 0xFFFFFFFFull);
                float inc = __uint_as_float((unsigned)(bb >> 32));
                int old = colm[j];
                colm[j] = i;
                rowm[i] = j;
                if (old) rowm[old] = 0;
                v0[j - 1] -= inc;
            }
        }
        __syncthreads();
    }

    // ---- u-fixup: u_i = rowmin(red_i) for all rows; drop non-tight ----
    for (int q = wv; q < N; q += 16) {
        int i = q + 1;
        float red[16];
        rowRed16(i, red);
        int j = rowm[i];                    // wave-uniform (LDS broadcast)
        // extract red at matched col before destroying red[]
        float rloc = red[0];
        int lo = 0, kk = 0;
        if (j) {
            lo = (j - 1) >> 4; kk = (j - 1) & 15;
#pragma unroll
            for (int k = 1; k < 16; ++k) if (k == kk) rloc = red[k];
        }
        // destructive tree min
#pragma unroll
        for (int s = 1; s < 16; s <<= 1) {
#pragma unroll
            for (int k = 0; k < 16; k += 2 * s)
                red[k] = fminf(red[k], red[k + s]);
        }
        float m = wave_min_f32(red[0]);
        if (j) {
            float rm = __int_as_float(
                __builtin_amdgcn_readlane(__float_as_int(rloc), lo));
            if (lane == 0 && rm != m) { rowm[i] = 0; colm[j] = 0; }
        }
        if (lane == 0) Uw[b * N + q] = m;
    }
    __syncthreads();

    // ---- write state for the SSP kernel ----
    for (int c = tid; c < N; c += 1024) {
        Vw[b * N + c] = v0[c];
        Cw[b * N + c] = colm[c + 1];
    }
    for (int t = tid; t < N; t += 1024) Rw[b * N + t] = rowm[t + 1];
}

struct Frag { uint4 w0, w1; float ur; float4 q; };

template<bool CACHED, bool PRE>
__global__ __launch_bounds__(64, 1)
void emd_jv_kernel(const float* __restrict__ S1,
                   const float* __restrict__ S2,
                   const __half* __restrict__ Dc,
                   const float* __restrict__ Vin,
                   const int*   __restrict__ Iin,
                   const float* __restrict__ Uw,
                   const int*   __restrict__ Cw,
                   const int*   __restrict__ Rw,
                   float* __restrict__ out) {
    __shared__ float4 s1u[N + 1];     // row coords (both modes; final fp32 sum)
    __shared__ float  u_lds[N + 1];   // row potentials
    __shared__ float  dentry[N + 1];  // D value when column settled
    __shared__ int    rowm[N + 1];    // row -> matched col (0 = free)

    const int lane = threadIdx.x;
    const int b = blockIdx.x;
    const float* s1g = S1 + (size_t)b * N * 3;
    const float* s2g = S2 + (size_t)b * N * 3;
    const __half* Db = CACHED ? (Dc + ((size_t)b << 20)) : (const __half*)0;
    const float NANF = __int_as_float(0x7fc00000);

    for (int t = lane; t < N; t += 64) {
        s1u[t + 1] = make_float4(s1g[3 * t], s1g[3 * t + 1], s1g[3 * t + 2], 0.0f);
        u_lds[t + 1] = PRE ? Uw[b * N + t] : 0.0f;
        rowm[t + 1] = PRE ? Rw[b * N + t] : 0;
    }
    if (lane == 0) { u_lds[0] = 0.0f; rowm[0] = 0; }

    // ---- per-lane column state: col j = c+1, c = lane*16+k ----
    float v[NSLOT];       // column potentials
    int   pr[NSLOT];      // matched row (0 = free)
    int   jpk[NSLOT];     // packed (pr<<11)|j
    float x2[NSLOT], y2[NSLOT], z2[NSLOT];  // S2 coords (final fp32 sum)

#pragma unroll
    for (int k = 0; k < NSLOT; ++k) {
        int pt = lane * NSLOT + k;
        x2[k] = s2g[3 * pt + 0];
        y2[k] = s2g[3 * pt + 1];
        z2[k] = s2g[3 * pt + 2];
    }

    if constexpr (PRE) {
#pragma unroll
        for (int k = 0; k < NSLOT; ++k) {
            int c = lane * NSLOT + k;
            v[k] = Vin[b * N + c];        // Vin = auction-updated v
            pr[k] = Cw[b * N + c];
            jpk[k] = (pr[k] << 11) | (c + 1);
        }
        __syncthreads();
    } else {
        int imin[NSLOT];
        if constexpr (CACHED) {
#pragma unroll
            for (int k = 0; k < NSLOT; ++k) {
                int c = lane * NSLOT + k;
                v[k] = Vin[b * N + c];
                imin[k] = Iin[b * N + c];
            }
        } else {
#pragma unroll
            for (int k = 0; k < NSLOT; ++k) { v[k] = INFV; imin[k] = 1; }
        }
        __syncthreads();

        if constexpr (!CACHED) {
            for (int r = 1; r <= N; ++r) {
                float4 qq = s1u[r];
#pragma unroll
                for (int k = 0; k < NSLOT; ++k) {
                    float dx = qq.x - x2[k], dy = qq.y - y2[k], dz = qq.z - z2[k];
                    float d2 = dx * dx + dy * dy + dz * dz;
                    bool upd = d2 < v[k];
                    v[k] = upd ? d2 : v[k];
                    imin[k] = upd ? r : imin[k];
                }
            }
#pragma unroll
            for (int k = 0; k < NSLOT; ++k) v[k] = sqrtf(v[k]);
        }

        // greedy matching on tight edges
#pragma unroll
        for (int k = 0; k < NSLOT; ++k) {
            int j = lane * NSLOT + k + 1;
            int r = imin[k];
            int old = atomicCAS(&rowm[r], 0, j);
            pr[k] = (old == 0) ? r : 0;
            jpk[k] = (pr[k] << 11) | j;
        }
        __syncthreads();
    }

    float minv[NSLOT];
    int   way[NSLOT];

    // issue row-r loads (cost-row fragment + u[r]); consumer waits only these
    auto issueLoads = [&](int rr) -> Frag {
        Frag F;
        if (CACHED) {
            const uint4* dr = (const uint4*)(Db + (size_t)(rr - 1) * N);
            F.w0 = dr[lane * 2 + 0];       // 8 halves
            F.w1 = dr[lane * 2 + 1];       // 8 halves
        } else {
            F.q = s1u[rr];
        }
        F.ur = u_lds[rr];
        return F;
    };

    auto applyFrag = [&](const Frag& F, int jpred, float Dh) {
        float base = Dh - F.ur;
        if (CACHED) {
            float h[NSLOT];
            const unsigned* w = (const unsigned*)&F.w0;   // w0,w1 contiguous
#pragma unroll
            for (int t = 0; t < 8; ++t) {
                unsigned word = w[t];
                __half2 hh = *reinterpret_cast<const __half2*>(&word);
                float2 f2 = __half22float2(hh);
                h[2 * t] = f2.x; h[2 * t + 1] = f2.y;
            }
#pragma unroll
            for (int k = 0; k < NSLOT; ++k) {
                float cur = (h[k] - v[k]) + base;
                bool upd = cur < minv[k];         // false for NaN (settled)
                minv[k] = upd ? cur : minv[k];
                way[k] = upd ? jpred : way[k];
            }
        } else {
#pragma unroll
            for (int k = 0; k < NSLOT; ++k) {
                float dx = F.q.x - x2[k], dy = F.q.y - y2[k], dz = F.q.z - z2[k];
                float d = sqrtf(dx * dx + dy * dy + dz * dz);
                float cur = (d - v[k]) + base;
                bool upd = cur < minv[k];
                minv[k] = upd ? cur : minv[k];
                way[k] = upd ? jpred : way[k];
            }
        }
    };

    // ---- successive shortest paths for free rows (exact on C') ----
    for (int i = 1; i <= N; ++i) {
        if (rowm[i] != 0) continue;

        unsigned used = 0u;
        float DT = 0.0f;
        int freecol = 0;
        int pred = 0;      // speculative prefetch: predicted next winner row
        Frag P;            // only read when pred != 0 (assigned then)

        Frag F0 = issueLoads(i);          // overlaps minv/way init
#pragma unroll
        for (int k = 0; k < NSLOT; ++k) { minv[k] = INFV; way[k] = 0; }
        applyFrag(F0, 0, 0.0f);

        int guard = 0;
        for (;;) {
            if (++guard > N + 4) break;
            // local argmin: 4 independent depth-4 chains + 2-level merge.
            float b0 = INFV, b1 = INFV, b2 = INFV, b3 = INFV;
            int   p0 = 0, p1 = 0, p2 = 0, p3 = 0;
#pragma unroll
            for (int k = 0; k < 4; ++k) {
                bool t0 = minv[k]      < b0;
                b0 = t0 ? minv[k]      : b0;  p0 = t0 ? jpk[k]      : p0;
                bool t1 = minv[k + 4]  < b1;
                b1 = t1 ? minv[k + 4]  : b1;  p1 = t1 ? jpk[k + 4]  : p1;
                bool t2 = minv[k + 8]  < b2;
                b2 = t2 ? minv[k + 8]  : b2;  p2 = t2 ? jpk[k + 8]  : p2;
                bool t3 = minv[k + 12] < b3;
                b3 = t3 ? minv[k + 12] : b3;  p3 = t3 ? jpk[k + 12] : p3;
            }
            bool m01 = b1 < b0;  float ba = m01 ? b1 : b0;  int pa = m01 ? p1 : p0;
            bool m23 = b3 < b2;  float bb = m23 ? b3 : b2;  int pb = m23 ? p3 : p2;
            bool mab = bb < ba;  float bestv = mab ? bb : ba;
            int bestjp = mab ? pb : pa;

            float gmin = wave_min_f32(bestv);
            if (!(gmin < INFV * 0.5f)) break;
            unsigned long long tm = __ballot(bestv == gmin);
            DT = gmin;
            freecol = 0;

            // 1) free-column short-circuit: zero expands if any tie is free
            {
                unsigned long long tf = tm;
                while (tf) {
                    int l = __ffsll((long long)tf) - 1;
                    tf &= tf - 1;
                    int jp = __builtin_amdgcn_readlane(bestjp, l);
                    if ((jp >> 11) == 0) { freecol = jp & 0x7FF; break; }
                }
            }
            if (freecol) break;

            // 2) settle all matched ties at gmin
            bool first = true;
            while (tm) {
                int l = __ffsll((long long)tm) - 1;
                tm &= tm - 1;
                int jp = __builtin_amdgcn_readlane(bestjp, l);
                int jj = jp & 0x7FF, rr = jp >> 11;
                Frag F;
                if (CACHED && first && pred != 0 && rr == pred) {
                    F = P;                         // prefetch hit: data resident
                } else {
                    F = issueLoads(rr);            // loads fly during marking
                }
                if (CACHED && first) {
                    // runner-up prefetch for the NEXT round; the wave-min +
                    // ballot here hides under the winner's L2 load latency.
                    float ru = (bestv == gmin) ? INFV : bestv;
                    float rmin = wave_min_f32(ru);
                    pred = 0;
                    if (rmin < INFV * 0.5f) {
                        unsigned long long rb = __ballot(ru == rmin);
                        int rl = __ffsll((long long)rb) - 1;
                        int rjp = __builtin_amdgcn_readlane(bestjp, rl);
                        int prr = rjp >> 11;
                        if (prr != 0) { pred = prr; P = issueLoads(prr); }
                    }
                }
                first = false;
                if (lane == 0) dentry[jj] = gmin;
                int cc = jj - 1, lo = cc >> 4, kk = cc & 15;
                bool mine = (lane == lo);
#pragma unroll
                for (int k = 0; k < NSLOT; ++k)
                    if (k == kk && mine) { minv[k] = NANF; used |= (1u << k); }
                applyFrag(F, jj, gmin);
            }
        }
        if (freecol == 0) continue;

        // deferred dual updates (pre-augment pr)
        if (lane == 0) u_lds[i] += DT;
#pragma unroll
        for (int k = 0; k < NSLOT; ++k) {
            if ((used >> k) & 1u) {
                int j = lane * NSLOT + k + 1;
                float dd = DT - dentry[j];
                v[k] -= dd;
                u_lds[pr[k]] += dd;      // distinct rows: race-free
            }
        }
        __syncthreads();

        // augment along alternating path (register p via readlanes)
        int j0 = freecol;
        int aguard = 0;
        while (j0 != 0) {
            if (++aguard > N + 4) break;
            int cc = j0 - 1;
            int lo = cc >> 4, kk = cc & 15;
            int wloc = way[0];
#pragma unroll
            for (int k = 1; k < NSLOT; ++k) if (k == kk) wloc = way[k];
            int j1 = __builtin_amdgcn_readlane(wloc, lo);
            int np;
            if (j1 == 0) np = i;
            else {
                int c1 = j1 - 1;
                int lo1 = c1 >> 4, kk1 = c1 & 15;
                int ploc = pr[0];
#pragma unroll
                for (int k = 1; k < NSLOT; ++k) if (k == kk1) ploc = pr[k];
                np = __builtin_amdgcn_readlane(ploc, lo1);
            }
            bool mine = (lane == lo);
#pragma unroll
            for (int k = 0; k < NSLOT; ++k)
                if (k == kk) {
                    if (mine) { pr[k] = np; jpk[k] = (np << 11) | j0; }
                }
            if (lane == 0) rowm[np] = j0;
            j0 = j1;
        }
        __syncthreads();
    }

    // ---- total matched cost: exact fp32 from coordinates ----
    float sum = 0.0f;
#pragma unroll
    for (int k = 0; k < NSLOT; ++k) {
        int r = pr[k] > 0 ? pr[k] : 1;
        float4 qq = s1u[r];
        float dx = qq.x - x2[k], dy = qq.y - y2[k], dz = qq.z - z2[k];
        sum += sqrtf(dx * dx + dy * dy + dz * dz);
    }
#pragma unroll
    for (int off = 32; off >= 1; off >>= 1) sum += __shfl_xor(sum, off);
    if (lane == 0) atomicAdd(out, sum * (1.0f / ((float)N * (float)BATCH)));
}

extern "C" void kernel_launch(void* const* d_in, const int* in_sizes, int n_in,
                              void* d_out, int out_size, void* d_ws, size_t ws_size,
                              hipStream_t stream) {
    const float* S1 = (const float*)d_in[0];
    const float* S2 = (const float*)d_in[1];
    float* out = (float*)d_out;

    size_t needD  = (size_t)BATCH * N * N * sizeof(__half);
    size_t vecB   = (size_t)BATCH * N * 4;            // one per-col/per-row array
    size_t needT  = needD + 2 * vecB;                 // V + I            (R8 tier)
    size_t needT2 = needD + 6 * vecB;                 // + Vw,Uw,Cw,Rw    (R13 tier)

    emd_zero_kernel<<<1, 1, 0, stream>>>(out);

    if (ws_size >= needT2) {
        __half* D  = (__half*)d_ws;
        float*  V  = (float*)((char*)d_ws + needD);
        int*    I  = (int*)((char*)V + vecB);
        float*  Vw = (float*)((char*)I + vecB);
        float*  Uw = (float*)((char*)Vw + vecB);
        int*    Cw = (int*)((char*)Uw + vecB);
        int*    Rw = (int*)((char*)Cw + vecB);
        emd_dist_kernel<<<BATCH * N, 256, 0, stream>>>(S1, S2, D);
        emd_colmin_kernel<<<BATCH * 4, 256, 0, stream>>>(D, V, I);
        emd_auction_kernel<<<BATCH, 1024, 0, stream>>>(D, V, I, Vw, Uw, Cw, Rw);
        emd_jv_kernel<true, true><<<BATCH, 64, 0, stream>>>(
            S1, S2, D, Vw, nullptr, Uw, Cw, Rw, out);
    } else if (ws_size >= needT) {
        __half* D = (__half*)d_ws;
        float*  V = (float*)((char*)d_ws + needD);
        int*    I = (int*)((char*)V + vecB);
        emd_dist_kernel<<<BATCH * N, 256, 0, stream>>>(S1, S2, D);
        emd_colmin_kernel<<<BATCH * 4, 256, 0, stream>>>(D, V, I);
        emd_jv_kernel<true, false><<<BATCH, 64, 0, stream>>>(
            S1, S2, D, V, I, nullptr, nullptr, nullptr, out);
    } else {
        emd_jv_kernel<false, false><<<BATCH, 64, 0, stream>>>(
            S1, S2, nullptr, nullptr, nullptr, nullptr, nullptr, nullptr, out);
    }
}

// Round 10
// 17370.346 us; speedup vs baseline: 1.1512x; 1.0251x over previous
//
#include <hip/hip_runtime.h>
#include <hip/hip_fp16.h>
#include <math.h>

// EarthMoverDistance: exact Hungarian (JV successive shortest path).
// B=8, N=1024, 3-D Euclidean cost. SSP: one wave per batch; lane owns 16
// columns (c = lane*16+k) in registers.
// R16 (base = R15, 17.81 ms; jv BYTE-IDENTICAL again — auction-only round):
//  - Two-phase auction with MID DROP-FIXUP: after 48 rounds, drop any
//    match with red(i,j) != rowmin_i (same check as final u-fixup, no Uw
//    write) and let those rows RE-BID for 24 more rounds at current
//    (lower) prices. Previously they were silently dumped on serial SSP.
//  - Rotating occupied-tie pick: when a tie set has no free column,
//    alternate lowest/highest tied column by round parity — breaks the
//    deterministic 2-cycles that fixed-lowest picking creates.
//  Correctness unconditional: prices only decrease (red >= 0 preserved);
//  final u-fixup enforces red == rowmin on every kept match, so SSP gets
//  an exactly feasible dual pair no matter what the heuristics do.
//  R15 attribution: auction prefer-free was worth -0.7ms jv; R14's jv
//  settle-pipeline was the regression (dead). Parallel-phase quality
//  still converts ~1:1 into serial-SSP savings -> keep pushing it.
// fp16 cost matrix in d_ws (2 MB/batch, XCD-L2 resident); FINAL SUM
// recomputed in fp32 from coords (absmax 0.0 across R6-R15 variants).

#define N     1024
#define BATCH 8
#define NSLOT 16          // columns per lane (SSP)
#define INFV  1e9f
#define AUC_R1 48         // phase-1 bidding rounds
#define AUC_R2 24         // phase-2 bidding rounds (post mid-fixup)

__global__ void emd_zero_kernel(float* out) { out[0] = 0.0f; }

// ---- cost cache: D[b][r][c] = fp16(dist(S1[b][r], S2[b][c])) ----
__global__ __launch_bounds__(256)
void emd_dist_kernel(const float* __restrict__ S1, const float* __restrict__ S2,
                     __half* __restrict__ D) {
    int b = blockIdx.x >> 10;
    int r = blockIdx.x & (N - 1);
    const float* s1 = S1 + ((size_t)b * N + r) * 3;
    float x1 = s1[0], y1 = s1[1], z1 = s1[2];
    const float* s2 = S2 + (size_t)b * N * 3;
    __half* drow = D + ((size_t)b * N + r) * (size_t)N;
    for (int c = threadIdx.x; c < N; c += 256) {
        float dx = x1 - s2[3 * c], dy = y1 - s2[3 * c + 1], dz = z1 - s2[3 * c + 2];
        drow[c] = __float2half_rn(sqrtf(dx * dx + dy * dy + dz * dz));
    }
}

// ---- column reduction over the fp16 matrix: v[c] = min_r C'(r,c) ----
__global__ __launch_bounds__(256)
void emd_colmin_kernel(const __half* __restrict__ D, float* __restrict__ V,
                       int* __restrict__ I) {
    int b = blockIdx.x >> 2;
    int c = ((blockIdx.x & 3) << 8) + threadIdx.x;
    const __half* Db = D + ((size_t)b << 20);
    float best = INFV; int bi = 1;
    for (int r = 0; r < N; ++r) {
        float d = __half2float(Db[(size_t)r * N + c]);
        if (d < best) { best = d; bi = r + 1; }
    }
    V[b * N + c] = best;
    I[b * N + c] = bi;
}

template<int CTRL>
__device__ __forceinline__ float dppmin(float x) {
    int xi = __float_as_int(x);
    int yi = __builtin_amdgcn_update_dpp(xi, xi, CTRL, 0xF, 0xF, false);
    return fminf(x, __int_as_float(yi));
}

__device__ __forceinline__ float wave_min_f32(float x) {
    x = dppmin<0x111>(x);   // row_shr:1
    x = dppmin<0x112>(x);   // row_shr:2
    x = dppmin<0x114>(x);   // row_shr:4
    x = dppmin<0x118>(x);   // row_shr:8
    x = dppmin<0x142>(x);   // row_bcast:15
    x = dppmin<0x143>(x);   // row_bcast:31 -> lane 63 has global min
    return __int_as_float(__builtin_amdgcn_readlane(__float_as_int(x), 63));
}

// ---- parallel auction initializer: 1024 threads (16 waves) per batch ----
// Invariants on exit (enforced by final u-fixup): red(i,j)=C'(i,j)-u_i-v_j
// >= 0 for all i,j (u_i = rowmin); red == 0 on every kept match.
__global__ __launch_bounds__(1024, 1)
void emd_auction_kernel(const __half* __restrict__ Dc,
                        const float* __restrict__ Vin,
                        const int* __restrict__ Iin,
                        float* __restrict__ Vw, float* __restrict__ Uw,
                        int* __restrict__ Cw, int* __restrict__ Rw) {
    __shared__ float v0[N];                 // column potentials, 0-indexed
    __shared__ int   rowm[N + 1];           // row -> col (1-idx), 0 = free
    __shared__ int   colm[N + 1];           // col -> row (1-idx), 0 = free
    __shared__ unsigned long long bid[N + 1];
    __shared__ int   qbuf[N];
    __shared__ int   qn;

    const int tid  = threadIdx.x;
    const int lane = tid & 63;
    const int wv   = tid >> 6;              // wave id 0..15
    const int b    = blockIdx.x;
    const __half* Db = Dc + ((size_t)b << 20);

    for (int t = tid; t <= N; t += 1024) { rowm[t] = 0; colm[t] = 0; bid[t] = 0ull; }
    for (int c = tid; c < N; c += 1024) v0[c] = Vin[b * N + c];
    __syncthreads();

    // greedy on tight edges (column -> its argmin row from colmin kernel)
    for (int c = tid; c < N; c += 1024) {
        int r = Iin[b * N + c];             // 1-indexed row
        int old = atomicCAS(&rowm[r], 0, c + 1);
        if (old == 0) colm[c + 1] = r;
    }
    __syncthreads();

    // per-wave row scan: red[k] = C'(i, lane*16+k) - v0[...]
    auto rowRed16 = [&](int i, float (&red)[16]) {
        const uint4* dr = (const uint4*)(Db + (size_t)(i - 1) * N);
        uint4 w0 = dr[lane * 2 + 0];
        uint4 w1 = dr[lane * 2 + 1];
        unsigned wb[8] = { w0.x, w0.y, w0.z, w0.w, w1.x, w1.y, w1.z, w1.w };
        const float4* vp = (const float4*)(v0 + lane * 16);   // 64B aligned
        float4 vv0 = vp[0], vv1 = vp[1], vv2 = vp[2], vv3 = vp[3];
        float vv[16] = { vv0.x, vv0.y, vv0.z, vv0.w, vv1.x, vv1.y, vv1.z, vv1.w,
                         vv2.x, vv2.y, vv2.z, vv2.w, vv3.x, vv3.y, vv3.z, vv3.w };
#pragma unroll
        for (int t = 0; t < 8; ++t) {
            __half2 hh = *reinterpret_cast<const __half2*>(&wb[t]);
            float2 f2 = __half22float2(hh);
            red[2 * t]     = f2.x - vv[2 * t];
            red[2 * t + 1] = f2.y - vv[2 * t + 1];
        }
    };

    // ---- bidding rounds (shared by both phases) ----
    auto runRounds = [&](int nrounds) {
        for (int round = 0; round < nrounds; ++round) {
            if (tid == 0) qn = 0;
            __syncthreads();
            for (int i = tid + 1; i <= N; i += 1024)
                if (rowm[i] == 0) { int p = atomicAdd(&qn, 1); qbuf[p] = i; }
            __syncthreads();
            int nq = qn;
            if (nq == 0) break;

            for (int q = wv; q < nq; q += 16) {
                int i = qbuf[q];
                float red[16];
                rowRed16(i, red);
                // local (min, secmin, argmin-col 0-idx): 4 chains of depth 4
                float a1 = INFV, a2 = INFV; int ac = 0;
                float e1 = INFV, e2 = INFV; int ec = 0;
                float f1 = INFV, f2 = INFV; int fc = 0;
                float g1 = INFV, g2 = INFV; int gc = 0;
#pragma unroll
                for (int k = 0; k < 4; ++k) {
                    float u0 = red[k];
                    bool t0 = u0 < a1;
                    a2 = t0 ? a1 : (u0 < a2 ? u0 : a2);
                    ac = t0 ? (lane * 16 + k) : ac;  a1 = t0 ? u0 : a1;
                    float u1 = red[k + 4];
                    bool t1 = u1 < e1;
                    e2 = t1 ? e1 : (u1 < e2 ? u1 : e2);
                    ec = t1 ? (lane * 16 + k + 4) : ec;  e1 = t1 ? u1 : e1;
                    float u2 = red[k + 8];
                    bool t2 = u2 < f1;
                    f2 = t2 ? f1 : (u2 < f2 ? u2 : f2);
                    fc = t2 ? (lane * 16 + k + 8) : fc;  f1 = t2 ? u2 : f1;
                    float u3 = red[k + 12];
                    bool t3 = u3 < g1;
                    g2 = t3 ? g1 : (u3 < g2 ? u3 : g2);
                    gc = t3 ? (lane * 16 + k + 12) : gc;  g1 = t3 ? u3 : g1;
                }
                bool sae = e1 < a1;
                float ae1 = sae ? e1 : a1; int aec = sae ? ec : ac;
                float ae2 = fminf(fminf(a2, e2), sae ? a1 : e1);
                bool sfg = g1 < f1;
                float fg1 = sfg ? g1 : f1; int fgc = sfg ? gc : fc;
                float fg2 = fminf(fminf(f2, g2), sfg ? f1 : g1);
                bool sall = fg1 < ae1;
                float m1 = sall ? fg1 : ae1;
                int   c1 = sall ? fgc : aec;
                float m2 = fminf(fminf(ae2, fg2), sall ? ae1 : fg1);

                // wave argmin with payload (uniform results on all lanes)
                float gm1 = wave_min_f32(m1);
                unsigned long long wbm = __ballot(m1 == gm1);
                int wl = __ffsll((long long)wbm) - 1;
                float cand2 = (lane == wl) ? m2 : m1;
                float gm2 = wave_min_f32(cand2);
                int gcol;
                if (gm1 < gm2) {
                    gcol = __builtin_amdgcn_readlane(c1, wl);  // unique argmin
                } else {
                    // ties: prefer a FREE tied column; else rotate the
                    // occupied pick (lowest/highest by round parity) to
                    // break deterministic displacement 2-cycles.
                    unsigned tmask = 0u;
#pragma unroll
                    for (int k = 0; k < 16; ++k)
                        tmask |= (red[k] == gm1) ? (1u << k) : 0u;
                    unsigned fmask = 0u;
                    unsigned tt = tmask;
                    while (tt) {
                        int k = __ffs((int)tt) - 1;
                        tt &= tt - 1;
                        if (colm[lane * 16 + k + 1] == 0) fmask |= (1u << k);
                    }
                    unsigned long long bf = __ballot(fmask != 0u);
                    if (bf != 0ull) {
                        int l = __ffsll((long long)bf) - 1;
                        unsigned mk = (unsigned)__builtin_amdgcn_readlane((int)fmask, l);
                        gcol = l * 16 + (__ffs((int)mk) - 1);
                    } else if (round & 1) {
                        unsigned long long ba = __ballot(tmask != 0u);
                        int l = 63 - __clzll(ba);               // highest lane
                        unsigned mk = (unsigned)__builtin_amdgcn_readlane((int)tmask, l);
                        gcol = l * 16 + (31 - __clz((int)mk));  // highest col
                    } else {
                        gcol = __builtin_amdgcn_readlane(c1, wl); // lowest col
                    }
                }
                float inc = gm2 - gm1;                          // >= 0

                if (lane == 0) {
                    unsigned long long key =
                        ((unsigned long long)__float_as_uint(inc) << 32) |
                        (unsigned long long)(unsigned)i;
                    atomicMax(&bid[gcol + 1], key);
                }
            }
            __syncthreads();

            // acceptance: column j takes its best bid; displaced row freed
            for (int j = tid + 1; j <= N; j += 1024) {
                unsigned long long bb = bid[j];
                if (bb != 0ull) {
                    bid[j] = 0ull;
                    int i = (int)(unsigned)(bb & 0xFFFFFFFFull);
                    float inc = __uint_as_float((unsigned)(bb >> 32));
                    int old = colm[j];
                    colm[j] = i;
                    rowm[i] = j;
                    if (old) rowm[old] = 0;
                    v0[j - 1] -= inc;
                }
            }
            __syncthreads();
        }
    };

    // ---- phase 1 ----
    runRounds(AUC_R1);

    // ---- mid drop-fixup: free any non-tight match, let it re-bid ----
    for (int q = wv; q < N; q += 16) {
        int i = q + 1;
        int j = rowm[i];                    // wave-uniform (LDS broadcast)
        if (j == 0) continue;               // only matched rows need checking
        float red[16];
        rowRed16(i, red);
        int lo = (j - 1) >> 4, kk = (j - 1) & 15;
        float rloc = red[0];
#pragma unroll
        for (int k = 1; k < 16; ++k) if (k == kk) rloc = red[k];
#pragma unroll
        for (int s = 1; s < 16; s <<= 1) {
#pragma unroll
            for (int k = 0; k < 16; k += 2 * s)
                red[k] = fminf(red[k], red[k + s]);
        }
        float m = wave_min_f32(red[0]);
        float rm = __int_as_float(
            __builtin_amdgcn_readlane(__float_as_int(rloc), lo));
        if (lane == 0 && rm != m) { rowm[i] = 0; colm[j] = 0; }
    }
    __syncthreads();

    // ---- phase 2 ----
    runRounds(AUC_R2);

    // ---- final u-fixup: u_i = rowmin(red_i); drop non-tight ----
    for (int q = wv; q < N; q += 16) {
        int i = q + 1;
        float red[16];
        rowRed16(i, red);
        int j = rowm[i];                    // wave-uniform (LDS broadcast)
        float rloc = red[0];
        int lo = 0, kk = 0;
        if (j) {
            lo = (j - 1) >> 4; kk = (j - 1) & 15;
#pragma unroll
            for (int k = 1; k < 16; ++k) if (k == kk) rloc = red[k];
        }
#pragma unroll
        for (int s = 1; s < 16; s <<= 1) {
#pragma unroll
            for (int k = 0; k < 16; k += 2 * s)
                red[k] = fminf(red[k], red[k + s]);
        }
        float m = wave_min_f32(red[0]);
        if (j) {
            float rm = __int_as_float(
                __builtin_amdgcn_readlane(__float_as_int(rloc), lo));
            if (lane == 0 && rm != m) { rowm[i] = 0; colm[j] = 0; }
        }
        if (lane == 0) Uw[b * N + q] = m;
    }
    __syncthreads();

    // ---- write state for the SSP kernel ----
    for (int c = tid; c < N; c += 1024) {
        Vw[b * N + c] = v0[c];
        Cw[b * N + c] = colm[c + 1];
    }
    for (int t = tid; t < N; t += 1024) Rw[b * N + t] = rowm[t + 1];
}

struct Frag { uint4 w0, w1; float ur; float4 q; };

template<bool CACHED, bool PRE>
__global__ __launch_bounds__(64, 1)
void emd_jv_kernel(const float* __restrict__ S1,
                   const float* __restrict__ S2,
                   const __half* __restrict__ Dc,
                   const float* __restrict__ Vin,
                   const int*   __restrict__ Iin,
                   const float* __restrict__ Uw,
                   const int*   __restrict__ Cw,
                   const int*   __restrict__ Rw,
                   float* __restrict__ out) {
    __shared__ float4 s1u[N + 1];     // row coords (both modes; final fp32 sum)
    __shared__ float  u_lds[N + 1];   // row potentials
    __shared__ float  dentry[N + 1];  // D value when column settled
    __shared__ int    rowm[N + 1];    // row -> matched col (0 = free)

    const int lane = threadIdx.x;
    const int b = blockIdx.x;
    const float* s1g = S1 + (size_t)b * N * 3;
    const float* s2g = S2 + (size_t)b * N * 3;
    const __half* Db = CACHED ? (Dc + ((size_t)b << 20)) : (const __half*)0;
    const float NANF = __int_as_float(0x7fc00000);

    for (int t = lane; t < N; t += 64) {
        s1u[t + 1] = make_float4(s1g[3 * t], s1g[3 * t + 1], s1g[3 * t + 2], 0.0f);
        u_lds[t + 1] = PRE ? Uw[b * N + t] : 0.0f;
        rowm[t + 1] = PRE ? Rw[b * N + t] : 0;
    }
    if (lane == 0) { u_lds[0] = 0.0f; rowm[0] = 0; }

    // ---- per-lane column state: col j = c+1, c = lane*16+k ----
    float v[NSLOT];       // column potentials
    int   pr[NSLOT];      // matched row (0 = free)
    int   jpk[NSLOT];     // packed (pr<<11)|j
    float x2[NSLOT], y2[NSLOT], z2[NSLOT];  // S2 coords (final fp32 sum)

#pragma unroll
    for (int k = 0; k < NSLOT; ++k) {
        int pt = lane * NSLOT + k;
        x2[k] = s2g[3 * pt + 0];
        y2[k] = s2g[3 * pt + 1];
        z2[k] = s2g[3 * pt + 2];
    }

    if constexpr (PRE) {
#pragma unroll
        for (int k = 0; k < NSLOT; ++k) {
            int c = lane * NSLOT + k;
            v[k] = Vin[b * N + c];        // Vin = auction-updated v
            pr[k] = Cw[b * N + c];
            jpk[k] = (pr[k] << 11) | (c + 1);
        }
        __syncthreads();
    } else {
        int imin[NSLOT];
        if constexpr (CACHED) {
#pragma unroll
            for (int k = 0; k < NSLOT; ++k) {
                int c = lane * NSLOT + k;
                v[k] = Vin[b * N + c];
                imin[k] = Iin[b * N + c];
            }
        } else {
#pragma unroll
            for (int k = 0; k < NSLOT; ++k) { v[k] = INFV; imin[k] = 1; }
        }
        __syncthreads();

        if constexpr (!CACHED) {
            for (int r = 1; r <= N; ++r) {
                float4 qq = s1u[r];
#pragma unroll
                for (int k = 0; k < NSLOT; ++k) {
                    float dx = qq.x - x2[k], dy = qq.y - y2[k], dz = qq.z - z2[k];
                    float d2 = dx * dx + dy * dy + dz * dz;
                    bool upd = d2 < v[k];
                    v[k] = upd ? d2 : v[k];
                    imin[k] = upd ? r : imin[k];
                }
            }
#pragma unroll
            for (int k = 0; k < NSLOT; ++k) v[k] = sqrtf(v[k]);
        }

        // greedy matching on tight edges
#pragma unroll
        for (int k = 0; k < NSLOT; ++k) {
            int j = lane * NSLOT + k + 1;
            int r = imin[k];
            int old = atomicCAS(&rowm[r], 0, j);
            pr[k] = (old == 0) ? r : 0;
            jpk[k] = (pr[k] << 11) | j;
        }
        __syncthreads();
    }

    float minv[NSLOT];
    int   way[NSLOT];

    // issue row-r loads (cost-row fragment + u[r]); consumer waits only these
    auto issueLoads = [&](int rr) -> Frag {
        Frag F;
        if (CACHED) {
            const uint4* dr = (const uint4*)(Db + (size_t)(rr - 1) * N);
            F.w0 = dr[lane * 2 + 0];       // 8 halves
            F.w1 = dr[lane * 2 + 1];       // 8 halves
        } else {
            F.q = s1u[rr];
        }
        F.ur = u_lds[rr];
        return F;
    };

    auto applyFrag = [&](const Frag& F, int jpred, float Dh) {
        float base = Dh - F.ur;
        if (CACHED) {
            float h[NSLOT];
            const unsigned* w = (const unsigned*)&F.w0;   // w0,w1 contiguous
#pragma unroll
            for (int t = 0; t < 8; ++t) {
                unsigned word = w[t];
                __half2 hh = *reinterpret_cast<const __half2*>(&word);
                float2 f2 = __half22float2(hh);
                h[2 * t] = f2.x; h[2 * t + 1] = f2.y;
            }
#pragma unroll
            for (int k = 0; k < NSLOT; ++k) {
                float cur = (h[k] - v[k]) + base;
                bool upd = cur < minv[k];         // false for NaN (settled)
                minv[k] = upd ? cur : minv[k];
                way[k] = upd ? jpred : way[k];
            }
        } else {
#pragma unroll
            for (int k = 0; k < NSLOT; ++k) {
                float dx = F.q.x - x2[k], dy = F.q.y - y2[k], dz = F.q.z - z2[k];
                float d = sqrtf(dx * dx + dy * dy + dz * dz);
                float cur = (d - v[k]) + base;
                bool upd = cur < minv[k];
                minv[k] = upd ? cur : minv[k];
                way[k] = upd ? jpred : way[k];
            }
        }
    };

    // ---- successive shortest paths for free rows (exact on C') ----
    for (int i = 1; i <= N; ++i) {
        if (rowm[i] != 0) continue;

        unsigned used = 0u;
        float DT = 0.0f;
        int freecol = 0;
        int pred = 0;      // speculative prefetch: predicted next winner row
        Frag P;            // only read when pred != 0 (assigned then)

        Frag F0 = issueLoads(i);          // overlaps minv/way init
#pragma unroll
        for (int k = 0; k < NSLOT; ++k) { minv[k] = INFV; way[k] = 0; }
        applyFrag(F0, 0, 0.0f);

        int guard = 0;
        for (;;) {
            if (++guard > N + 4) break;
            // local argmin: 4 independent depth-4 chains + 2-level merge.
            float b0 = INFV, b1 = INFV, b2 = INFV, b3 = INFV;
            int   p0 = 0, p1 = 0, p2 = 0, p3 = 0;
#pragma unroll
            for (int k = 0; k < 4; ++k) {
                bool t0 = minv[k]      < b0;
                b0 = t0 ? minv[k]      : b0;  p0 = t0 ? jpk[k]      : p0;
                bool t1 = minv[k + 4]  < b1;
                b1 = t1 ? minv[k + 4]  : b1;  p1 = t1 ? jpk[k + 4]  : p1;
                bool t2 = minv[k + 8]  < b2;
                b2 = t2 ? minv[k + 8]  : b2;  p2 = t2 ? jpk[k + 8]  : p2;
                bool t3 = minv[k + 12] < b3;
                b3 = t3 ? minv[k + 12] : b3;  p3 = t3 ? jpk[k + 12] : p3;
            }
            bool m01 = b1 < b0;  float ba = m01 ? b1 : b0;  int pa = m01 ? p1 : p0;
            bool m23 = b3 < b2;  float bb = m23 ? b3 : b2;  int pb = m23 ? p3 : p2;
            bool mab = bb < ba;  float bestv = mab ? bb : ba;
            int bestjp = mab ? pb : pa;

            float gmin = wave_min_f32(bestv);
            if (!(gmin < INFV * 0.5f)) break;
            unsigned long long tm = __ballot(bestv == gmin);
            DT = gmin;
            freecol = 0;

            // 1) free-column short-circuit: zero expands if any tie is free
            {
                unsigned long long tf = tm;
                while (tf) {
                    int l = __ffsll((long long)tf) - 1;
                    tf &= tf - 1;
                    int jp = __builtin_amdgcn_readlane(bestjp, l);
                    if ((jp >> 11) == 0) { freecol = jp & 0x7FF; break; }
                }
            }
            if (freecol) break;

            // 2) settle all matched ties at gmin
            bool first = true;
            while (tm) {
                int l = __ffsll((long long)tm) - 1;
                tm &= tm - 1;
                int jp = __builtin_amdgcn_readlane(bestjp, l);
                int jj = jp & 0x7FF, rr = jp >> 11;
                Frag F;
                if (CACHED && first && pred != 0 && rr == pred) {
                    F = P;                         // prefetch hit: data resident
                } else {
                    F = issueLoads(rr);            // loads fly during marking
                }
                if (CACHED && first) {
                    // runner-up prefetch for the NEXT round; the wave-min +
                    // ballot here hides under the winner's L2 load latency.
                    float ru = (bestv == gmin) ? INFV : bestv;
                    float rmin = wave_min_f32(ru);
                    pred = 0;
                    if (rmin < INFV * 0.5f) {
                        unsigned long long rb = __ballot(ru == rmin);
                        int rl = __ffsll((long long)rb) - 1;
                        int rjp = __builtin_amdgcn_readlane(bestjp, rl);
                        int prr = rjp >> 11;
                        if (prr != 0) { pred = prr; P = issueLoads(prr); }
                    }
                }
                first = false;
                if (lane == 0) dentry[jj] = gmin;
                int cc = jj - 1, lo = cc >> 4, kk = cc & 15;
                bool mine = (lane == lo);
#pragma unroll
                for (int k = 0; k < NSLOT; ++k)
                    if (k == kk && mine) { minv[k] = NANF; used |= (1u << k); }
                applyFrag(F, jj, gmin);
            }
        }
        if (freecol == 0) continue;

        // deferred dual updates (pre-augment pr)
        if (lane == 0) u_lds[i] += DT;
#pragma unroll
        for (int k = 0; k < NSLOT; ++k) {
            if ((used >> k) & 1u) {
                int j = lane * NSLOT + k + 1;
                float dd = DT - dentry[j];
                v[k] -= dd;
                u_lds[pr[k]] += dd;      // distinct rows: race-free
            }
        }
        __syncthreads();

        // augment along alternating path (register p via readlanes)
        int j0 = freecol;
        int aguard = 0;
        while (j0 != 0) {
            if (++aguard > N + 4) break;
            int cc = j0 - 1;
            int lo = cc >> 4, kk = cc & 15;
            int wloc = way[0];
#pragma unroll
            for (int k = 1; k < NSLOT; ++k) if (k == kk) wloc = way[k];
            int j1 = __builtin_amdgcn_readlane(wloc, lo);
            int np;
            if (j1 == 0) np = i;
            else {
                int c1 = j1 - 1;
                int lo1 = c1 >> 4, kk1 = c1 & 15;
                int ploc = pr[0];
#pragma unroll
                for (int k = 1; k < NSLOT; ++k) if (k == kk1) ploc = pr[k];
                np = __builtin_amdgcn_readlane(ploc, lo1);
            }
            bool mine = (lane == lo);
#pragma unroll
            for (int k = 0; k < NSLOT; ++k)
                if (k == kk) {
                    if (mine) { pr[k] = np; jpk[k] = (np << 11) | j0; }
                }
            if (lane == 0) rowm[np] = j0;
            j0 = j1;
        }
        __syncthreads();
    }

    // ---- total matched cost: exact fp32 from coordinates ----
    float sum = 0.0f;
#pragma unroll
    for (int k = 0; k < NSLOT; ++k) {
        int r = pr[k] > 0 ? pr[k] : 1;
        float4 qq = s1u[r];
        float dx = qq.x - x2[k], dy = qq.y - y2[k], dz = qq.z - z2[k];
        sum += sqrtf(dx * dx + dy * dy + dz * dz);
    }
#pragma unroll
    for (int off = 32; off >= 1; off >>= 1) sum += __shfl_xor(sum, off);
    if (lane == 0) atomicAdd(out, sum * (1.0f / ((float)N * (float)BATCH)));
}

extern "C" void kernel_launch(void* const* d_in, const int* in_sizes, int n_in,
                              void* d_out, int out_size, void* d_ws, size_t ws_size,
                              hipStream_t stream) {
    const float* S1 = (const float*)d_in[0];
    const float* S2 = (const float*)d_in[1];
    float* out = (float*)d_out;

    size_t needD  = (size_t)BATCH * N * N * sizeof(__half);
    size_t vecB   = (size_t)BATCH * N * 4;            // one per-col/per-row array
    size_t needT  = needD + 2 * vecB;                 // V + I            (R8 tier)
    size_t needT2 = needD + 6 * vecB;                 // + Vw,Uw,Cw,Rw    (R13 tier)

    emd_zero_kernel<<<1, 1, 0, stream>>>(out);

    if (ws_size >= needT2) {
        __half* D  = (__half*)d_ws;
        float*  V  = (float*)((char*)d_ws + needD);
        int*    I  = (int*)((char*)V + vecB);
        float*  Vw = (float*)((char*)I + vecB);
        float*  Uw = (float*)((char*)Vw + vecB);
        int*    Cw = (int*)((char*)Uw + vecB);
        int*    Rw = (int*)((char*)Cw + vecB);
        emd_dist_kernel<<<BATCH * N, 256, 0, stream>>>(S1, S2, D);
        emd_colmin_kernel<<<BATCH * 4, 256, 0, stream>>>(D, V, I);
        emd_auction_kernel<<<BATCH, 1024, 0, stream>>>(D, V, I, Vw, Uw, Cw, Rw);
        emd_jv_kernel<true, true><<<BATCH, 64, 0, stream>>>(
            S1, S2, D, Vw, nullptr, Uw, Cw, Rw, out);
    } else if (ws_size >= needT) {
        __half* D = (__half*)d_ws;
        float*  V = (float*)((char*)d_ws + needD);
        int*    I = (int*)((char*)V + vecB);
        emd_dist_kernel<<<BATCH * N, 256, 0, stream>>>(S1, S2, D);
        emd_colmin_kernel<<<BATCH * 4, 256, 0, stream>>>(D, V, I);
        emd_jv_kernel<true, false><<<BATCH, 64, 0, stream>>>(
            S1, S2, D, V, I, nullptr, nullptr, nullptr, out);
    } else {
        emd_jv_kernel<false, false><<<BATCH, 64, 0, stream>>>(
            S1, S2, nullptr, nullptr, nullptr, nullptr, nullptr, nullptr, out);
    }
}

// Round 11
// 15522.931 us; speedup vs baseline: 1.2882x; 1.1190x over previous
//
#include <hip/hip_runtime.h>
#include <hip/hip_fp16.h>
#include <math.h>

// EarthMoverDistance: exact Hungarian (JV successive shortest path).
// B=8, N=1024, 3-D Euclidean cost. SSP: one wave per batch; lane owns 16
// columns (c = lane*16+k) in registers.
// R17 (base = R16, 17.37 ms):
//  - Auction: finer drop-rebid interleave — 32 initial rounds, then
//    5 x {drop-fixup; 16 rounds} (R16: one fixup after 48). A dropped
//    non-tight row that re-bids its argmin column lands TIGHT at the new
//    price by construction, so frequent fixup+rebid converges toward an
//    all-tight matching. Parity rotation carried across phases.
//    Correctness unconditional: prices only decrease (red >= 0), final
//    u-fixup enforces red == rowmin on every kept match.
//  - jv: single-ballot free-column short-circuit — one
//    __ballot(tie && free) replaces the serial readlane tie-scan.
//    Provably identical selection (lowest qualifying lane either way),
//    ~30-40 cy off every settle round. Semantics bit-identical => any
//    state-quality delta stays attributable to the auction change.
//  R15/R16 lesson held twice: rows the auction leaves tightly-matched
//  are ~1:1 serial-SSP time deleted. Keep converting.
// fp16 cost matrix in d_ws (2 MB/batch, XCD-L2 resident); FINAL SUM
// recomputed in fp32 from coords (absmax 0.0 across R6-R16 variants).

#define N     1024
#define BATCH 8
#define NSLOT 16          // columns per lane (SSP)
#define INFV  1e9f
#define AUC_R1 32         // initial bidding rounds
#define AUC_RP 16         // rounds per drop-rebid phase
#define AUC_PHASES 5      // drop-rebid phases

__global__ void emd_zero_kernel(float* out) { out[0] = 0.0f; }

// ---- cost cache: D[b][r][c] = fp16(dist(S1[b][r], S2[b][c])) ----
__global__ __launch_bounds__(256)
void emd_dist_kernel(const float* __restrict__ S1, const float* __restrict__ S2,
                     __half* __restrict__ D) {
    int b = blockIdx.x >> 10;
    int r = blockIdx.x & (N - 1);
    const float* s1 = S1 + ((size_t)b * N + r) * 3;
    float x1 = s1[0], y1 = s1[1], z1 = s1[2];
    const float* s2 = S2 + (size_t)b * N * 3;
    __half* drow = D + ((size_t)b * N + r) * (size_t)N;
    for (int c = threadIdx.x; c < N; c += 256) {
        float dx = x1 - s2[3 * c], dy = y1 - s2[3 * c + 1], dz = z1 - s2[3 * c + 2];
        drow[c] = __float2half_rn(sqrtf(dx * dx + dy * dy + dz * dz));
    }
}

// ---- column reduction over the fp16 matrix: v[c] = min_r C'(r,c) ----
__global__ __launch_bounds__(256)
void emd_colmin_kernel(const __half* __restrict__ D, float* __restrict__ V,
                       int* __restrict__ I) {
    int b = blockIdx.x >> 2;
    int c = ((blockIdx.x & 3) << 8) + threadIdx.x;
    const __half* Db = D + ((size_t)b << 20);
    float best = INFV; int bi = 1;
    for (int r = 0; r < N; ++r) {
        float d = __half2float(Db[(size_t)r * N + c]);
        if (d < best) { best = d; bi = r + 1; }
    }
    V[b * N + c] = best;
    I[b * N + c] = bi;
}

template<int CTRL>
__device__ __forceinline__ float dppmin(float x) {
    int xi = __float_as_int(x);
    int yi = __builtin_amdgcn_update_dpp(xi, xi, CTRL, 0xF, 0xF, false);
    return fminf(x, __int_as_float(yi));
}

__device__ __forceinline__ float wave_min_f32(float x) {
    x = dppmin<0x111>(x);   // row_shr:1
    x = dppmin<0x112>(x);   // row_shr:2
    x = dppmin<0x114>(x);   // row_shr:4
    x = dppmin<0x118>(x);   // row_shr:8
    x = dppmin<0x142>(x);   // row_bcast:15
    x = dppmin<0x143>(x);   // row_bcast:31 -> lane 63 has global min
    return __int_as_float(__builtin_amdgcn_readlane(__float_as_int(x), 63));
}

// ---- parallel auction initializer: 1024 threads (16 waves) per batch ----
// Invariants on exit (enforced by final u-fixup): red(i,j)=C'(i,j)-u_i-v_j
// >= 0 for all i,j (u_i = rowmin); red == 0 on every kept match.
__global__ __launch_bounds__(1024, 1)
void emd_auction_kernel(const __half* __restrict__ Dc,
                        const float* __restrict__ Vin,
                        const int* __restrict__ Iin,
                        float* __restrict__ Vw, float* __restrict__ Uw,
                        int* __restrict__ Cw, int* __restrict__ Rw) {
    __shared__ float v0[N];                 // column potentials, 0-indexed
    __shared__ int   rowm[N + 1];           // row -> col (1-idx), 0 = free
    __shared__ int   colm[N + 1];           // col -> row (1-idx), 0 = free
    __shared__ unsigned long long bid[N + 1];
    __shared__ int   qbuf[N];
    __shared__ int   qn;

    const int tid  = threadIdx.x;
    const int lane = tid & 63;
    const int wv   = tid >> 6;              // wave id 0..15
    const int b    = blockIdx.x;
    const __half* Db = Dc + ((size_t)b << 20);

    for (int t = tid; t <= N; t += 1024) { rowm[t] = 0; colm[t] = 0; bid[t] = 0ull; }
    for (int c = tid; c < N; c += 1024) v0[c] = Vin[b * N + c];
    __syncthreads();

    // greedy on tight edges (column -> its argmin row from colmin kernel)
    for (int c = tid; c < N; c += 1024) {
        int r = Iin[b * N + c];             // 1-indexed row
        int old = atomicCAS(&rowm[r], 0, c + 1);
        if (old == 0) colm[c + 1] = r;
    }
    __syncthreads();

    // per-wave row scan: red[k] = C'(i, lane*16+k) - v0[...]
    auto rowRed16 = [&](int i, float (&red)[16]) {
        const uint4* dr = (const uint4*)(Db + (size_t)(i - 1) * N);
        uint4 w0 = dr[lane * 2 + 0];
        uint4 w1 = dr[lane * 2 + 1];
        unsigned wb[8] = { w0.x, w0.y, w0.z, w0.w, w1.x, w1.y, w1.z, w1.w };
        const float4* vp = (const float4*)(v0 + lane * 16);   // 64B aligned
        float4 vv0 = vp[0], vv1 = vp[1], vv2 = vp[2], vv3 = vp[3];
        float vv[16] = { vv0.x, vv0.y, vv0.z, vv0.w, vv1.x, vv1.y, vv1.z, vv1.w,
                         vv2.x, vv2.y, vv2.z, vv2.w, vv3.x, vv3.y, vv3.z, vv3.w };
#pragma unroll
        for (int t = 0; t < 8; ++t) {
            __half2 hh = *reinterpret_cast<const __half2*>(&wb[t]);
            float2 f2 = __half22float2(hh);
            red[2 * t]     = f2.x - vv[2 * t];
            red[2 * t + 1] = f2.y - vv[2 * t + 1];
        }
    };

    // ---- bidding rounds (rbase carries tie-rotation parity across calls) ----
    auto runRounds = [&](int nrounds, int rbase) {
        for (int round = 0; round < nrounds; ++round) {
            if (tid == 0) qn = 0;
            __syncthreads();
            for (int i = tid + 1; i <= N; i += 1024)
                if (rowm[i] == 0) { int p = atomicAdd(&qn, 1); qbuf[p] = i; }
            __syncthreads();
            int nq = qn;
            if (nq == 0) break;

            for (int q = wv; q < nq; q += 16) {
                int i = qbuf[q];
                float red[16];
                rowRed16(i, red);
                // local (min, secmin, argmin-col 0-idx): 4 chains of depth 4
                float a1 = INFV, a2 = INFV; int ac = 0;
                float e1 = INFV, e2 = INFV; int ec = 0;
                float f1 = INFV, f2 = INFV; int fc = 0;
                float g1 = INFV, g2 = INFV; int gc = 0;
#pragma unroll
                for (int k = 0; k < 4; ++k) {
                    float u0 = red[k];
                    bool t0 = u0 < a1;
                    a2 = t0 ? a1 : (u0 < a2 ? u0 : a2);
                    ac = t0 ? (lane * 16 + k) : ac;  a1 = t0 ? u0 : a1;
                    float u1 = red[k + 4];
                    bool t1 = u1 < e1;
                    e2 = t1 ? e1 : (u1 < e2 ? u1 : e2);
                    ec = t1 ? (lane * 16 + k + 4) : ec;  e1 = t1 ? u1 : e1;
                    float u2 = red[k + 8];
                    bool t2 = u2 < f1;
                    f2 = t2 ? f1 : (u2 < f2 ? u2 : f2);
                    fc = t2 ? (lane * 16 + k + 8) : fc;  f1 = t2 ? u2 : f1;
                    float u3 = red[k + 12];
                    bool t3 = u3 < g1;
                    g2 = t3 ? g1 : (u3 < g2 ? u3 : g2);
                    gc = t3 ? (lane * 16 + k + 12) : gc;  g1 = t3 ? u3 : g1;
                }
                bool sae = e1 < a1;
                float ae1 = sae ? e1 : a1; int aec = sae ? ec : ac;
                float ae2 = fminf(fminf(a2, e2), sae ? a1 : e1);
                bool sfg = g1 < f1;
                float fg1 = sfg ? g1 : f1; int fgc = sfg ? gc : fc;
                float fg2 = fminf(fminf(f2, g2), sfg ? f1 : g1);
                bool sall = fg1 < ae1;
                float m1 = sall ? fg1 : ae1;
                int   c1 = sall ? fgc : aec;
                float m2 = fminf(fminf(ae2, fg2), sall ? ae1 : fg1);

                // wave argmin with payload (uniform results on all lanes)
                float gm1 = wave_min_f32(m1);
                unsigned long long wbm = __ballot(m1 == gm1);
                int wl = __ffsll((long long)wbm) - 1;
                float cand2 = (lane == wl) ? m2 : m1;
                float gm2 = wave_min_f32(cand2);
                int gcol;
                if (gm1 < gm2) {
                    gcol = __builtin_amdgcn_readlane(c1, wl);  // unique argmin
                } else {
                    // ties: prefer a FREE tied column; else rotate the
                    // occupied pick (lowest/highest by parity) to break
                    // deterministic displacement 2-cycles.
                    unsigned tmask = 0u;
#pragma unroll
                    for (int k = 0; k < 16; ++k)
                        tmask |= (red[k] == gm1) ? (1u << k) : 0u;
                    unsigned fmask = 0u;
                    unsigned tt = tmask;
                    while (tt) {
                        int k = __ffs((int)tt) - 1;
                        tt &= tt - 1;
                        if (colm[lane * 16 + k + 1] == 0) fmask |= (1u << k);
                    }
                    unsigned long long bf = __ballot(fmask != 0u);
                    if (bf != 0ull) {
                        int l = __ffsll((long long)bf) - 1;
                        unsigned mk = (unsigned)__builtin_amdgcn_readlane((int)fmask, l);
                        gcol = l * 16 + (__ffs((int)mk) - 1);
                    } else if ((rbase + round) & 1) {
                        unsigned long long ba = __ballot(tmask != 0u);
                        int l = 63 - __clzll(ba);               // highest lane
                        unsigned mk = (unsigned)__builtin_amdgcn_readlane((int)tmask, l);
                        gcol = l * 16 + (31 - __clz((int)mk));  // highest col
                    } else {
                        gcol = __builtin_amdgcn_readlane(c1, wl); // lowest col
                    }
                }
                float inc = gm2 - gm1;                          // >= 0

                if (lane == 0) {
                    unsigned long long key =
                        ((unsigned long long)__float_as_uint(inc) << 32) |
                        (unsigned long long)(unsigned)i;
                    atomicMax(&bid[gcol + 1], key);
                }
            }
            __syncthreads();

            // acceptance: column j takes its best bid; displaced row freed
            for (int j = tid + 1; j <= N; j += 1024) {
                unsigned long long bb = bid[j];
                if (bb != 0ull) {
                    bid[j] = 0ull;
                    int i = (int)(unsigned)(bb & 0xFFFFFFFFull);
                    float inc = __uint_as_float((unsigned)(bb >> 32));
                    int old = colm[j];
                    colm[j] = i;
                    rowm[i] = j;
                    if (old) rowm[old] = 0;
                    v0[j - 1] -= inc;
                }
            }
            __syncthreads();
        }
    };

    // drop any non-tight match (red != rowmin), freeing it to re-bid
    auto midFixup = [&]() {
        for (int q = wv; q < N; q += 16) {
            int i = q + 1;
            int j = rowm[i];                // wave-uniform (LDS broadcast)
            if (j == 0) continue;
            float red[16];
            rowRed16(i, red);
            int lo = (j - 1) >> 4, kk = (j - 1) & 15;
            float rloc = red[0];
#pragma unroll
            for (int k = 1; k < 16; ++k) if (k == kk) rloc = red[k];
#pragma unroll
            for (int s = 1; s < 16; s <<= 1) {
#pragma unroll
                for (int k = 0; k < 16; k += 2 * s)
                    red[k] = fminf(red[k], red[k + s]);
            }
            float m = wave_min_f32(red[0]);
            float rm = __int_as_float(
                __builtin_amdgcn_readlane(__float_as_int(rloc), lo));
            if (lane == 0 && rm != m) { rowm[i] = 0; colm[j] = 0; }
        }
    };

    // ---- phase schedule: 32 rounds, then 5 x {fixup; 16 rounds} ----
    runRounds(AUC_R1, 0);
    for (int ph = 0; ph < AUC_PHASES; ++ph) {
        midFixup();
        __syncthreads();
        runRounds(AUC_RP, ph);
    }

    // ---- final u-fixup: u_i = rowmin(red_i); drop non-tight ----
    for (int q = wv; q < N; q += 16) {
        int i = q + 1;
        float red[16];
        rowRed16(i, red);
        int j = rowm[i];                    // wave-uniform (LDS broadcast)
        float rloc = red[0];
        int lo = 0, kk = 0;
        if (j) {
            lo = (j - 1) >> 4; kk = (j - 1) & 15;
#pragma unroll
            for (int k = 1; k < 16; ++k) if (k == kk) rloc = red[k];
        }
#pragma unroll
        for (int s = 1; s < 16; s <<= 1) {
#pragma unroll
            for (int k = 0; k < 16; k += 2 * s)
                red[k] = fminf(red[k], red[k + s]);
        }
        float m = wave_min_f32(red[0]);
        if (j) {
            float rm = __int_as_float(
                __builtin_amdgcn_readlane(__float_as_int(rloc), lo));
            if (lane == 0 && rm != m) { rowm[i] = 0; colm[j] = 0; }
        }
        if (lane == 0) Uw[b * N + q] = m;
    }
    __syncthreads();

    // ---- write state for the SSP kernel ----
    for (int c = tid; c < N; c += 1024) {
        Vw[b * N + c] = v0[c];
        Cw[b * N + c] = colm[c + 1];
    }
    for (int t = tid; t < N; t += 1024) Rw[b * N + t] = rowm[t + 1];
}

struct Frag { uint4 w0, w1; float ur; float4 q; };

template<bool CACHED, bool PRE>
__global__ __launch_bounds__(64, 1)
void emd_jv_kernel(const float* __restrict__ S1,
                   const float* __restrict__ S2,
                   const __half* __restrict__ Dc,
                   const float* __restrict__ Vin,
                   const int*   __restrict__ Iin,
                   const float* __restrict__ Uw,
                   const int*   __restrict__ Cw,
                   const int*   __restrict__ Rw,
                   float* __restrict__ out) {
    __shared__ float4 s1u[N + 1];     // row coords (both modes; final fp32 sum)
    __shared__ float  u_lds[N + 1];   // row potentials
    __shared__ float  dentry[N + 1];  // D value when column settled
    __shared__ int    rowm[N + 1];    // row -> matched col (0 = free)

    const int lane = threadIdx.x;
    const int b = blockIdx.x;
    const float* s1g = S1 + (size_t)b * N * 3;
    const float* s2g = S2 + (size_t)b * N * 3;
    const __half* Db = CACHED ? (Dc + ((size_t)b << 20)) : (const __half*)0;
    const float NANF = __int_as_float(0x7fc00000);

    for (int t = lane; t < N; t += 64) {
        s1u[t + 1] = make_float4(s1g[3 * t], s1g[3 * t + 1], s1g[3 * t + 2], 0.0f);
        u_lds[t + 1] = PRE ? Uw[b * N + t] : 0.0f;
        rowm[t + 1] = PRE ? Rw[b * N + t] : 0;
    }
    if (lane == 0) { u_lds[0] = 0.0f; rowm[0] = 0; }

    // ---- per-lane column state: col j = c+1, c = lane*16+k ----
    float v[NSLOT];       // column potentials
    int   pr[NSLOT];      // matched row (0 = free)
    int   jpk[NSLOT];     // packed (pr<<11)|j
    float x2[NSLOT], y2[NSLOT], z2[NSLOT];  // S2 coords (final fp32 sum)

#pragma unroll
    for (int k = 0; k < NSLOT; ++k) {
        int pt = lane * NSLOT + k;
        x2[k] = s2g[3 * pt + 0];
        y2[k] = s2g[3 * pt + 1];
        z2[k] = s2g[3 * pt + 2];
    }

    if constexpr (PRE) {
#pragma unroll
        for (int k = 0; k < NSLOT; ++k) {
            int c = lane * NSLOT + k;
            v[k] = Vin[b * N + c];        // Vin = auction-updated v
            pr[k] = Cw[b * N + c];
            jpk[k] = (pr[k] << 11) | (c + 1);
        }
        __syncthreads();
    } else {
        int imin[NSLOT];
        if constexpr (CACHED) {
#pragma unroll
            for (int k = 0; k < NSLOT; ++k) {
                int c = lane * NSLOT + k;
                v[k] = Vin[b * N + c];
                imin[k] = Iin[b * N + c];
            }
        } else {
#pragma unroll
            for (int k = 0; k < NSLOT; ++k) { v[k] = INFV; imin[k] = 1; }
        }
        __syncthreads();

        if constexpr (!CACHED) {
            for (int r = 1; r <= N; ++r) {
                float4 qq = s1u[r];
#pragma unroll
                for (int k = 0; k < NSLOT; ++k) {
                    float dx = qq.x - x2[k], dy = qq.y - y2[k], dz = qq.z - z2[k];
                    float d2 = dx * dx + dy * dy + dz * dz;
                    bool upd = d2 < v[k];
                    v[k] = upd ? d2 : v[k];
                    imin[k] = upd ? r : imin[k];
                }
            }
#pragma unroll
            for (int k = 0; k < NSLOT; ++k) v[k] = sqrtf(v[k]);
        }

        // greedy matching on tight edges
#pragma unroll
        for (int k = 0; k < NSLOT; ++k) {
            int j = lane * NSLOT + k + 1;
            int r = imin[k];
            int old = atomicCAS(&rowm[r], 0, j);
            pr[k] = (old == 0) ? r : 0;
            jpk[k] = (pr[k] << 11) | j;
        }
        __syncthreads();
    }

    float minv[NSLOT];
    int   way[NSLOT];

    // issue row-r loads (cost-row fragment + u[r]); consumer waits only these
    auto issueLoads = [&](int rr) -> Frag {
        Frag F;
        if (CACHED) {
            const uint4* dr = (const uint4*)(Db + (size_t)(rr - 1) * N);
            F.w0 = dr[lane * 2 + 0];       // 8 halves
            F.w1 = dr[lane * 2 + 1];       // 8 halves
        } else {
            F.q = s1u[rr];
        }
        F.ur = u_lds[rr];
        return F;
    };

    auto applyFrag = [&](const Frag& F, int jpred, float Dh) {
        float base = Dh - F.ur;
        if (CACHED) {
            float h[NSLOT];
            const unsigned* w = (const unsigned*)&F.w0;   // w0,w1 contiguous
#pragma unroll
            for (int t = 0; t < 8; ++t) {
                unsigned word = w[t];
                __half2 hh = *reinterpret_cast<const __half2*>(&word);
                float2 f2 = __half22float2(hh);
                h[2 * t] = f2.x; h[2 * t + 1] = f2.y;
            }
#pragma unroll
            for (int k = 0; k < NSLOT; ++k) {
                float cur = (h[k] - v[k]) + base;
                bool upd = cur < minv[k];         // false for NaN (settled)
                minv[k] = upd ? cur : minv[k];
                way[k] = upd ? jpred : way[k];
            }
        } else {
#pragma unroll
            for (int k = 0; k < NSLOT; ++k) {
                float dx = F.q.x - x2[k], dy = F.q.y - y2[k], dz = F.q.z - z2[k];
                float d = sqrtf(dx * dx + dy * dy + dz * dz);
                float cur = (d - v[k]) + base;
                bool upd = cur < minv[k];
                minv[k] = upd ? cur : minv[k];
                way[k] = upd ? jpred : way[k];
            }
        }
    };

    // ---- successive shortest paths for free rows (exact on C') ----
    for (int i = 1; i <= N; ++i) {
        if (rowm[i] != 0) continue;

        unsigned used = 0u;
        float DT = 0.0f;
        int freecol = 0;
        int pred = 0;      // speculative prefetch: predicted next winner row
        Frag P;            // only read when pred != 0 (assigned then)

        Frag F0 = issueLoads(i);          // overlaps minv/way init
#pragma unroll
        for (int k = 0; k < NSLOT; ++k) { minv[k] = INFV; way[k] = 0; }
        applyFrag(F0, 0, 0.0f);

        int guard = 0;
        for (;;) {
            if (++guard > N + 4) break;
            // local argmin: 4 independent depth-4 chains + 2-level merge.
            float b0 = INFV, b1 = INFV, b2 = INFV, b3 = INFV;
            int   p0 = 0, p1 = 0, p2 = 0, p3 = 0;
#pragma unroll
            for (int k = 0; k < 4; ++k) {
                bool t0 = minv[k]      < b0;
                b0 = t0 ? minv[k]      : b0;  p0 = t0 ? jpk[k]      : p0;
                bool t1 = minv[k + 4]  < b1;
                b1 = t1 ? minv[k + 4]  : b1;  p1 = t1 ? jpk[k + 4]  : p1;
                bool t2 = minv[k + 8]  < b2;
                b2 = t2 ? minv[k + 8]  : b2;  p2 = t2 ? jpk[k + 8]  : p2;
                bool t3 = minv[k + 12] < b3;
                b3 = t3 ? minv[k + 12] : b3;  p3 = t3 ? jpk[k + 12] : p3;
            }
            bool m01 = b1 < b0;  float ba = m01 ? b1 : b0;  int pa = m01 ? p1 : p0;
            bool m23 = b3 < b2;  float bb = m23 ? b3 : b2;  int pb = m23 ? p3 : p2;
            bool mab = bb < ba;  float bestv = mab ? bb : ba;
            int bestjp = mab ? pb : pa;

            float gmin = wave_min_f32(bestv);
            if (!(gmin < INFV * 0.5f)) break;
            unsigned long long tm = __ballot(bestv == gmin);
            DT = gmin;
            freecol = 0;

            // 1) free-column short-circuit: single ballot (equivalent to
            //    scanning ties lowest-lane-first for a free bestjp)
            {
                unsigned long long tf =
                    __ballot((bestv == gmin) && ((bestjp >> 11) == 0));
                if (tf) {
                    int l = __ffsll((long long)tf) - 1;
                    freecol = __builtin_amdgcn_readlane(bestjp, l) & 0x7FF;
                }
            }
            if (freecol) break;

            // 2) settle all matched ties at gmin
            bool first = true;
            while (tm) {
                int l = __ffsll((long long)tm) - 1;
                tm &= tm - 1;
                int jp = __builtin_amdgcn_readlane(bestjp, l);
                int jj = jp & 0x7FF, rr = jp >> 11;
                Frag F;
                if (CACHED && first && pred != 0 && rr == pred) {
                    F = P;                         // prefetch hit: data resident
                } else {
                    F = issueLoads(rr);            // loads fly during marking
                }
                if (CACHED && first) {
                    // runner-up prefetch for the NEXT round; the wave-min +
                    // ballot here hides under the winner's L2 load latency.
                    float ru = (bestv == gmin) ? INFV : bestv;
                    float rmin = wave_min_f32(ru);
                    pred = 0;
                    if (rmin < INFV * 0.5f) {
                        unsigned long long rb = __ballot(ru == rmin);
                        int rl = __ffsll((long long)rb) - 1;
                        int rjp = __builtin_amdgcn_readlane(bestjp, rl);
                        int prr = rjp >> 11;
                        if (prr != 0) { pred = prr; P = issueLoads(prr); }
                    }
                }
                first = false;
                if (lane == 0) dentry[jj] = gmin;
                int cc = jj - 1, lo = cc >> 4, kk = cc & 15;
                bool mine = (lane == lo);
#pragma unroll
                for (int k = 0; k < NSLOT; ++k)
                    if (k == kk && mine) { minv[k] = NANF; used |= (1u << k); }
                applyFrag(F, jj, gmin);
            }
        }
        if (freecol == 0) continue;

        // deferred dual updates (pre-augment pr)
        if (lane == 0) u_lds[i] += DT;
#pragma unroll
        for (int k = 0; k < NSLOT; ++k) {
            if ((used >> k) & 1u) {
                int j = lane * NSLOT + k + 1;
                float dd = DT - dentry[j];
                v[k] -= dd;
                u_lds[pr[k]] += dd;      // distinct rows: race-free
            }
        }
        __syncthreads();

        // augment along alternating path (register p via readlanes)
        int j0 = freecol;
        int aguard = 0;
        while (j0 != 0) {
            if (++aguard > N + 4) break;
            int cc = j0 - 1;
            int lo = cc >> 4, kk = cc & 15;
            int wloc = way[0];
#pragma unroll
            for (int k = 1; k < NSLOT; ++k) if (k == kk) wloc = way[k];
            int j1 = __builtin_amdgcn_readlane(wloc, lo);
            int np;
            if (j1 == 0) np = i;
            else {
                int c1 = j1 - 1;
                int lo1 = c1 >> 4, kk1 = c1 & 15;
                int ploc = pr[0];
#pragma unroll
                for (int k = 1; k < NSLOT; ++k) if (k == kk1) ploc = pr[k];
                np = __builtin_amdgcn_readlane(ploc, lo1);
            }
            bool mine = (lane == lo);
#pragma unroll
            for (int k = 0; k < NSLOT; ++k)
                if (k == kk) {
                    if (mine) { pr[k] = np; jpk[k] = (np << 11) | j0; }
                }
            if (lane == 0) rowm[np] = j0;
            j0 = j1;
        }
        __syncthreads();
    }

    // ---- total matched cost: exact fp32 from coordinates ----
    float sum = 0.0f;
#pragma unroll
    for (int k = 0; k < NSLOT; ++k) {
        int r = pr[k] > 0 ? pr[k] : 1;
        float4 qq = s1u[r];
        float dx = qq.x - x2[k], dy = qq.y - y2[k], dz = qq.z - z2[k];
        sum += sqrtf(dx * dx + dy * dy + dz * dz);
    }
#pragma unroll
    for (int off = 32; off >= 1; off >>= 1) sum += __shfl_xor(sum, off);
    if (lane == 0) atomicAdd(out, sum * (1.0f / ((float)N * (float)BATCH)));
}

extern "C" void kernel_launch(void* const* d_in, const int* in_sizes, int n_in,
                              void* d_out, int out_size, void* d_ws, size_t ws_size,
                              hipStream_t stream) {
    const float* S1 = (const float*)d_in[0];
    const float* S2 = (const float*)d_in[1];
    float* out = (float*)d_out;

    size_t needD  = (size_t)BATCH * N * N * sizeof(__half);
    size_t vecB   = (size_t)BATCH * N * 4;            // one per-col/per-row array
    size_t needT  = needD + 2 * vecB;                 // V + I            (R8 tier)
    size_t needT2 = needD + 6 * vecB;                 // + Vw,Uw,Cw,Rw    (R13 tier)

    emd_zero_kernel<<<1, 1, 0, stream>>>(out);

    if (ws_size >= needT2) {
        __half* D  = (__half*)d_ws;
        float*  V  = (float*)((char*)d_ws + needD);
        int*    I  = (int*)((char*)V + vecB);
        float*  Vw = (float*)((char*)I + vecB);
        float*  Uw = (float*)((char*)Vw + vecB);
        int*    Cw = (int*)((char*)Uw + vecB);
        int*    Rw = (int*)((char*)Cw + vecB);
        emd_dist_kernel<<<BATCH * N, 256, 0, stream>>>(S1, S2, D);
        emd_colmin_kernel<<<BATCH * 4, 256, 0, stream>>>(D, V, I);
        emd_auction_kernel<<<BATCH, 1024, 0, stream>>>(D, V, I, Vw, Uw, Cw, Rw);
        emd_jv_kernel<true, true><<<BATCH, 64, 0, stream>>>(
            S1, S2, D, Vw, nullptr, Uw, Cw, Rw, out);
    } else if (ws_size >= needT) {
        __half* D = (__half*)d_ws;
        float*  V = (float*)((char*)d_ws + needD);
        int*    I = (int*)((char*)V + vecB);
        emd_dist_kernel<<<BATCH * N, 256, 0, stream>>>(S1, S2, D);
        emd_colmin_kernel<<<BATCH * 4, 256, 0, stream>>>(D, V, I);
        emd_jv_kernel<true, false><<<BATCH, 64, 0, stream>>>(
            S1, S2, D, V, I, nullptr, nullptr, nullptr, out);
    } else {
        emd_jv_kernel<false, false><<<BATCH, 64, 0, stream>>>(
            S1, S2, nullptr, nullptr, nullptr, nullptr, nullptr, nullptr, out);
    }
}

// Round 12
// 15366.489 us; speedup vs baseline: 1.3014x; 1.0102x over previous
//
#include <hip/hip_runtime.h>
#include <hip/hip_fp16.h>
#include <math.h>

// EarthMoverDistance: exact Hungarian (JV successive shortest path).
// B=8, N=1024, 3-D Euclidean cost. SSP: one wave per batch; lane owns 16
// columns (c = lane*16+k) in registers.
// R18 (base = R17, 15.52 ms; jv BYTE-IDENTICAL — auction-only round):
//  - Deeper drop-rebid schedule with CONVERGENCE EXIT: 32 initial rounds,
//    then up to 12 x {drop-fixup; count-free (LDS-only, ~2us); break if
//    fully matched; 12 rounds}. R17's 5x16 converted ~1:1 into jv savings
//    (17.45 -> 15.0); each phase costs ~0.1ms and the exit check makes
//    converged phases free.
//  - Correctness unconditional (R16/R17 argument): prices only decrease
//    => red >= 0 preserved; final u-fixup enforces red == rowmin on every
//    kept match; SSP catches all remnants exactly.
//  Trajectory: jv 22.0 -> 18.3 -> 17.45 -> 15.0 as auction state improved.
//  If jv flat this round => lever saturated, pivot to SSP round latency.
// fp16 cost matrix in d_ws (2 MB/batch, XCD-L2 resident); FINAL SUM
// recomputed in fp32 from coords (absmax 0.0 across R6-R17 variants).

#define N     1024
#define BATCH 8
#define NSLOT 16          // columns per lane (SSP)
#define INFV  1e9f
#define AUC_R1 32         // initial bidding rounds
#define AUC_RP 12         // rounds per drop-rebid phase
#define AUC_PHASES 12     // max drop-rebid phases (convergence exit)

__global__ void emd_zero_kernel(float* out) { out[0] = 0.0f; }

// ---- cost cache: D[b][r][c] = fp16(dist(S1[b][r], S2[b][c])) ----
__global__ __launch_bounds__(256)
void emd_dist_kernel(const float* __restrict__ S1, const float* __restrict__ S2,
                     __half* __restrict__ D) {
    int b = blockIdx.x >> 10;
    int r = blockIdx.x & (N - 1);
    const float* s1 = S1 + ((size_t)b * N + r) * 3;
    float x1 = s1[0], y1 = s1[1], z1 = s1[2];
    const float* s2 = S2 + (size_t)b * N * 3;
    __half* drow = D + ((size_t)b * N + r) * (size_t)N;
    for (int c = threadIdx.x; c < N; c += 256) {
        float dx = x1 - s2[3 * c], dy = y1 - s2[3 * c + 1], dz = z1 - s2[3 * c + 2];
        drow[c] = __float2half_rn(sqrtf(dx * dx + dy * dy + dz * dz));
    }
}

// ---- column reduction over the fp16 matrix: v[c] = min_r C'(r,c) ----
__global__ __launch_bounds__(256)
void emd_colmin_kernel(const __half* __restrict__ D, float* __restrict__ V,
                       int* __restrict__ I) {
    int b = blockIdx.x >> 2;
    int c = ((blockIdx.x & 3) << 8) + threadIdx.x;
    const __half* Db = D + ((size_t)b << 20);
    float best = INFV; int bi = 1;
    for (int r = 0; r < N; ++r) {
        float d = __half2float(Db[(size_t)r * N + c]);
        if (d < best) { best = d; bi = r + 1; }
    }
    V[b * N + c] = best;
    I[b * N + c] = bi;
}

template<int CTRL>
__device__ __forceinline__ float dppmin(float x) {
    int xi = __float_as_int(x);
    int yi = __builtin_amdgcn_update_dpp(xi, xi, CTRL, 0xF, 0xF, false);
    return fminf(x, __int_as_float(yi));
}

__device__ __forceinline__ float wave_min_f32(float x) {
    x = dppmin<0x111>(x);   // row_shr:1
    x = dppmin<0x112>(x);   // row_shr:2
    x = dppmin<0x114>(x);   // row_shr:4
    x = dppmin<0x118>(x);   // row_shr:8
    x = dppmin<0x142>(x);   // row_bcast:15
    x = dppmin<0x143>(x);   // row_bcast:31 -> lane 63 has global min
    return __int_as_float(__builtin_amdgcn_readlane(__float_as_int(x), 63));
}

// ---- parallel auction initializer: 1024 threads (16 waves) per batch ----
// Invariants on exit (enforced by final u-fixup): red(i,j)=C'(i,j)-u_i-v_j
// >= 0 for all i,j (u_i = rowmin); red == 0 on every kept match.
__global__ __launch_bounds__(1024, 1)
void emd_auction_kernel(const __half* __restrict__ Dc,
                        const float* __restrict__ Vin,
                        const int* __restrict__ Iin,
                        float* __restrict__ Vw, float* __restrict__ Uw,
                        int* __restrict__ Cw, int* __restrict__ Rw) {
    __shared__ float v0[N];                 // column potentials, 0-indexed
    __shared__ int   rowm[N + 1];           // row -> col (1-idx), 0 = free
    __shared__ int   colm[N + 1];           // col -> row (1-idx), 0 = free
    __shared__ unsigned long long bid[N + 1];
    __shared__ int   qbuf[N];
    __shared__ int   qn;

    const int tid  = threadIdx.x;
    const int lane = tid & 63;
    const int wv   = tid >> 6;              // wave id 0..15
    const int b    = blockIdx.x;
    const __half* Db = Dc + ((size_t)b << 20);

    for (int t = tid; t <= N; t += 1024) { rowm[t] = 0; colm[t] = 0; bid[t] = 0ull; }
    for (int c = tid; c < N; c += 1024) v0[c] = Vin[b * N + c];
    __syncthreads();

    // greedy on tight edges (column -> its argmin row from colmin kernel)
    for (int c = tid; c < N; c += 1024) {
        int r = Iin[b * N + c];             // 1-indexed row
        int old = atomicCAS(&rowm[r], 0, c + 1);
        if (old == 0) colm[c + 1] = r;
    }
    __syncthreads();

    // per-wave row scan: red[k] = C'(i, lane*16+k) - v0[...]
    auto rowRed16 = [&](int i, float (&red)[16]) {
        const uint4* dr = (const uint4*)(Db + (size_t)(i - 1) * N);
        uint4 w0 = dr[lane * 2 + 0];
        uint4 w1 = dr[lane * 2 + 1];
        unsigned wb[8] = { w0.x, w0.y, w0.z, w0.w, w1.x, w1.y, w1.z, w1.w };
        const float4* vp = (const float4*)(v0 + lane * 16);   // 64B aligned
        float4 vv0 = vp[0], vv1 = vp[1], vv2 = vp[2], vv3 = vp[3];
        float vv[16] = { vv0.x, vv0.y, vv0.z, vv0.w, vv1.x, vv1.y, vv1.z, vv1.w,
                         vv2.x, vv2.y, vv2.z, vv2.w, vv3.x, vv3.y, vv3.z, vv3.w };
#pragma unroll
        for (int t = 0; t < 8; ++t) {
            __half2 hh = *reinterpret_cast<const __half2*>(&wb[t]);
            float2 f2 = __half22float2(hh);
            red[2 * t]     = f2.x - vv[2 * t];
            red[2 * t + 1] = f2.y - vv[2 * t + 1];
        }
    };

    // ---- bidding rounds (rbase carries tie-rotation parity across calls) ----
    auto runRounds = [&](int nrounds, int rbase) {
        for (int round = 0; round < nrounds; ++round) {
            if (tid == 0) qn = 0;
            __syncthreads();
            for (int i = tid + 1; i <= N; i += 1024)
                if (rowm[i] == 0) { int p = atomicAdd(&qn, 1); qbuf[p] = i; }
            __syncthreads();
            int nq = qn;
            if (nq == 0) break;

            for (int q = wv; q < nq; q += 16) {
                int i = qbuf[q];
                float red[16];
                rowRed16(i, red);
                // local (min, secmin, argmin-col 0-idx): 4 chains of depth 4
                float a1 = INFV, a2 = INFV; int ac = 0;
                float e1 = INFV, e2 = INFV; int ec = 0;
                float f1 = INFV, f2 = INFV; int fc = 0;
                float g1 = INFV, g2 = INFV; int gc = 0;
#pragma unroll
                for (int k = 0; k < 4; ++k) {
                    float u0 = red[k];
                    bool t0 = u0 < a1;
                    a2 = t0 ? a1 : (u0 < a2 ? u0 : a2);
                    ac = t0 ? (lane * 16 + k) : ac;  a1 = t0 ? u0 : a1;
                    float u1 = red[k + 4];
                    bool t1 = u1 < e1;
                    e2 = t1 ? e1 : (u1 < e2 ? u1 : e2);
                    ec = t1 ? (lane * 16 + k + 4) : ec;  e1 = t1 ? u1 : e1;
                    float u2 = red[k + 8];
                    bool t2 = u2 < f1;
                    f2 = t2 ? f1 : (u2 < f2 ? u2 : f2);
                    fc = t2 ? (lane * 16 + k + 8) : fc;  f1 = t2 ? u2 : f1;
                    float u3 = red[k + 12];
                    bool t3 = u3 < g1;
                    g2 = t3 ? g1 : (u3 < g2 ? u3 : g2);
                    gc = t3 ? (lane * 16 + k + 12) : gc;  g1 = t3 ? u3 : g1;
                }
                bool sae = e1 < a1;
                float ae1 = sae ? e1 : a1; int aec = sae ? ec : ac;
                float ae2 = fminf(fminf(a2, e2), sae ? a1 : e1);
                bool sfg = g1 < f1;
                float fg1 = sfg ? g1 : f1; int fgc = sfg ? gc : fc;
                float fg2 = fminf(fminf(f2, g2), sfg ? f1 : g1);
                bool sall = fg1 < ae1;
                float m1 = sall ? fg1 : ae1;
                int   c1 = sall ? fgc : aec;
                float m2 = fminf(fminf(ae2, fg2), sall ? ae1 : fg1);

                // wave argmin with payload (uniform results on all lanes)
                float gm1 = wave_min_f32(m1);
                unsigned long long wbm = __ballot(m1 == gm1);
                int wl = __ffsll((long long)wbm) - 1;
                float cand2 = (lane == wl) ? m2 : m1;
                float gm2 = wave_min_f32(cand2);
                int gcol;
                if (gm1 < gm2) {
                    gcol = __builtin_amdgcn_readlane(c1, wl);  // unique argmin
                } else {
                    // ties: prefer a FREE tied column; else rotate the
                    // occupied pick (lowest/highest by parity) to break
                    // deterministic displacement 2-cycles.
                    unsigned tmask = 0u;
#pragma unroll
                    for (int k = 0; k < 16; ++k)
                        tmask |= (red[k] == gm1) ? (1u << k) : 0u;
                    unsigned fmask = 0u;
                    unsigned tt = tmask;
                    while (tt) {
                        int k = __ffs((int)tt) - 1;
                        tt &= tt - 1;
                        if (colm[lane * 16 + k + 1] == 0) fmask |= (1u << k);
                    }
                    unsigned long long bf = __ballot(fmask != 0u);
                    if (bf != 0ull) {
                        int l = __ffsll((long long)bf) - 1;
                        unsigned mk = (unsigned)__builtin_amdgcn_readlane((int)fmask, l);
                        gcol = l * 16 + (__ffs((int)mk) - 1);
                    } else if ((rbase + round) & 1) {
                        unsigned long long ba = __ballot(tmask != 0u);
                        int l = 63 - __clzll(ba);               // highest lane
                        unsigned mk = (unsigned)__builtin_amdgcn_readlane((int)tmask, l);
                        gcol = l * 16 + (31 - __clz((int)mk));  // highest col
                    } else {
                        gcol = __builtin_amdgcn_readlane(c1, wl); // lowest col
                    }
                }
                float inc = gm2 - gm1;                          // >= 0

                if (lane == 0) {
                    unsigned long long key =
                        ((unsigned long long)__float_as_uint(inc) << 32) |
                        (unsigned long long)(unsigned)i;
                    atomicMax(&bid[gcol + 1], key);
                }
            }
            __syncthreads();

            // acceptance: column j takes its best bid; displaced row freed
            for (int j = tid + 1; j <= N; j += 1024) {
                unsigned long long bb = bid[j];
                if (bb != 0ull) {
                    bid[j] = 0ull;
                    int i = (int)(unsigned)(bb & 0xFFFFFFFFull);
                    float inc = __uint_as_float((unsigned)(bb >> 32));
                    int old = colm[j];
                    colm[j] = i;
                    rowm[i] = j;
                    if (old) rowm[old] = 0;
                    v0[j - 1] -= inc;
                }
            }
            __syncthreads();
        }
    };

    // drop any non-tight match (red != rowmin), freeing it to re-bid
    auto midFixup = [&]() {
        for (int q = wv; q < N; q += 16) {
            int i = q + 1;
            int j = rowm[i];                // wave-uniform (LDS broadcast)
            if (j == 0) continue;
            float red[16];
            rowRed16(i, red);
            int lo = (j - 1) >> 4, kk = (j - 1) & 15;
            float rloc = red[0];
#pragma unroll
            for (int k = 1; k < 16; ++k) if (k == kk) rloc = red[k];
#pragma unroll
            for (int s = 1; s < 16; s <<= 1) {
#pragma unroll
                for (int k = 0; k < 16; k += 2 * s)
                    red[k] = fminf(red[k], red[k + s]);
            }
            float m = wave_min_f32(red[0]);
            float rm = __int_as_float(
                __builtin_amdgcn_readlane(__float_as_int(rloc), lo));
            if (lane == 0 && rm != m) { rowm[i] = 0; colm[j] = 0; }
        }
    };

    // ---- phase schedule: 32 rounds, then up to 12 x {fixup; exit?; 12} ----
    runRounds(AUC_R1, 0);
    for (int ph = 0; ph < AUC_PHASES; ++ph) {
        midFixup();
        __syncthreads();
        // convergence exit: fully matched (and fixup kept everything) => done
        if (tid == 0) qn = 0;
        __syncthreads();
        for (int i = tid + 1; i <= N; i += 1024)
            if (rowm[i] == 0) atomicAdd(&qn, 1);
        __syncthreads();
        if (qn == 0) break;
        runRounds(AUC_RP, ph);
    }

    // ---- final u-fixup: u_i = rowmin(red_i); drop non-tight ----
    for (int q = wv; q < N; q += 16) {
        int i = q + 1;
        float red[16];
        rowRed16(i, red);
        int j = rowm[i];                    // wave-uniform (LDS broadcast)
        float rloc = red[0];
        int lo = 0, kk = 0;
        if (j) {
            lo = (j - 1) >> 4; kk = (j - 1) & 15;
#pragma unroll
            for (int k = 1; k < 16; ++k) if (k == kk) rloc = red[k];
        }
#pragma unroll
        for (int s = 1; s < 16; s <<= 1) {
#pragma unroll
            for (int k = 0; k < 16; k += 2 * s)
                red[k] = fminf(red[k], red[k + s]);
        }
        float m = wave_min_f32(red[0]);
        if (j) {
            float rm = __int_as_float(
                __builtin_amdgcn_readlane(__float_as_int(rloc), lo));
            if (lane == 0 && rm != m) { rowm[i] = 0; colm[j] = 0; }
        }
        if (lane == 0) Uw[b * N + q] = m;
    }
    __syncthreads();

    // ---- write state for the SSP kernel ----
    for (int c = tid; c < N; c += 1024) {
        Vw[b * N + c] = v0[c];
        Cw[b * N + c] = colm[c + 1];
    }
    for (int t = tid; t < N; t += 1024) Rw[b * N + t] = rowm[t + 1];
}

struct Frag { uint4 w0, w1; float ur; float4 q; };

template<bool CACHED, bool PRE>
__global__ __launch_bounds__(64, 1)
void emd_jv_kernel(const float* __restrict__ S1,
                   const float* __restrict__ S2,
                   const __half* __restrict__ Dc,
                   const float* __restrict__ Vin,
                   const int*   __restrict__ Iin,
                   const float* __restrict__ Uw,
                   const int*   __restrict__ Cw,
                   const int*   __restrict__ Rw,
                   float* __restrict__ out) {
    __shared__ float4 s1u[N + 1];     // row coords (both modes; final fp32 sum)
    __shared__ float  u_lds[N + 1];   // row potentials
    __shared__ float  dentry[N + 1];  // D value when column settled
    __shared__ int    rowm[N + 1];    // row -> matched col (0 = free)

    const int lane = threadIdx.x;
    const int b = blockIdx.x;
    const float* s1g = S1 + (size_t)b * N * 3;
    const float* s2g = S2 + (size_t)b * N * 3;
    const __half* Db = CACHED ? (Dc + ((size_t)b << 20)) : (const __half*)0;
    const float NANF = __int_as_float(0x7fc00000);

    for (int t = lane; t < N; t += 64) {
        s1u[t + 1] = make_float4(s1g[3 * t], s1g[3 * t + 1], s1g[3 * t + 2], 0.0f);
        u_lds[t + 1] = PRE ? Uw[b * N + t] : 0.0f;
        rowm[t + 1] = PRE ? Rw[b * N + t] : 0;
    }
    if (lane == 0) { u_lds[0] = 0.0f; rowm[0] = 0; }

    // ---- per-lane column state: col j = c+1, c = lane*16+k ----
    float v[NSLOT];       // column potentials
    int   pr[NSLOT];      // matched row (0 = free)
    int   jpk[NSLOT];     // packed (pr<<11)|j
    float x2[NSLOT], y2[NSLOT], z2[NSLOT];  // S2 coords (final fp32 sum)

#pragma unroll
    for (int k = 0; k < NSLOT; ++k) {
        int pt = lane * NSLOT + k;
        x2[k] = s2g[3 * pt + 0];
        y2[k] = s2g[3 * pt + 1];
        z2[k] = s2g[3 * pt + 2];
    }

    if constexpr (PRE) {
#pragma unroll
        for (int k = 0; k < NSLOT; ++k) {
            int c = lane * NSLOT + k;
            v[k] = Vin[b * N + c];        // Vin = auction-updated v
            pr[k] = Cw[b * N + c];
            jpk[k] = (pr[k] << 11) | (c + 1);
        }
        __syncthreads();
    } else {
        int imin[NSLOT];
        if constexpr (CACHED) {
#pragma unroll
            for (int k = 0; k < NSLOT; ++k) {
                int c = lane * NSLOT + k;
                v[k] = Vin[b * N + c];
                imin[k] = Iin[b * N + c];
            }
        } else {
#pragma unroll
            for (int k = 0; k < NSLOT; ++k) { v[k] = INFV; imin[k] = 1; }
        }
        __syncthreads();

        if constexpr (!CACHED) {
            for (int r = 1; r <= N; ++r) {
                float4 qq = s1u[r];
#pragma unroll
                for (int k = 0; k < NSLOT; ++k) {
                    float dx = qq.x - x2[k], dy = qq.y - y2[k], dz = qq.z - z2[k];
                    float d2 = dx * dx + dy * dy + dz * dz;
                    bool upd = d2 < v[k];
                    v[k] = upd ? d2 : v[k];
                    imin[k] = upd ? r : imin[k];
                }
            }
#pragma unroll
            for (int k = 0; k < NSLOT; ++k) v[k] = sqrtf(v[k]);
        }

        // greedy matching on tight edges
#pragma unroll
        for (int k = 0; k < NSLOT; ++k) {
            int j = lane * NSLOT + k + 1;
            int r = imin[k];
            int old = atomicCAS(&rowm[r], 0, j);
            pr[k] = (old == 0) ? r : 0;
            jpk[k] = (pr[k] << 11) | j;
        }
        __syncthreads();
    }

    float minv[NSLOT];
    int   way[NSLOT];

    // issue row-r loads (cost-row fragment + u[r]); consumer waits only these
    auto issueLoads = [&](int rr) -> Frag {
        Frag F;
        if (CACHED) {
            const uint4* dr = (const uint4*)(Db + (size_t)(rr - 1) * N);
            F.w0 = dr[lane * 2 + 0];       // 8 halves
            F.w1 = dr[lane * 2 + 1];       // 8 halves
        } else {
            F.q = s1u[rr];
        }
        F.ur = u_lds[rr];
        return F;
    };

    auto applyFrag = [&](const Frag& F, int jpred, float Dh) {
        float base = Dh - F.ur;
        if (CACHED) {
            float h[NSLOT];
            const unsigned* w = (const unsigned*)&F.w0;   // w0,w1 contiguous
#pragma unroll
            for (int t = 0; t < 8; ++t) {
                unsigned word = w[t];
                __half2 hh = *reinterpret_cast<const __half2*>(&word);
                float2 f2 = __half22float2(hh);
                h[2 * t] = f2.x; h[2 * t + 1] = f2.y;
            }
#pragma unroll
            for (int k = 0; k < NSLOT; ++k) {
                float cur = (h[k] - v[k]) + base;
                bool upd = cur < minv[k];         // false for NaN (settled)
                minv[k] = upd ? cur : minv[k];
                way[k] = upd ? jpred : way[k];
            }
        } else {
#pragma unroll
            for (int k = 0; k < NSLOT; ++k) {
                float dx = F.q.x - x2[k], dy = F.q.y - y2[k], dz = F.q.z - z2[k];
                float d = sqrtf(dx * dx + dy * dy + dz * dz);
                float cur = (d - v[k]) + base;
                bool upd = cur < minv[k];
                minv[k] = upd ? cur : minv[k];
                way[k] = upd ? jpred : way[k];
            }
        }
    };

    // ---- successive shortest paths for free rows (exact on C') ----
    for (int i = 1; i <= N; ++i) {
        if (rowm[i] != 0) continue;

        unsigned used = 0u;
        float DT = 0.0f;
        int freecol = 0;
        int pred = 0;      // speculative prefetch: predicted next winner row
        Frag P;            // only read when pred != 0 (assigned then)

        Frag F0 = issueLoads(i);          // overlaps minv/way init
#pragma unroll
        for (int k = 0; k < NSLOT; ++k) { minv[k] = INFV; way[k] = 0; }
        applyFrag(F0, 0, 0.0f);

        int guard = 0;
        for (;;) {
            if (++guard > N + 4) break;
            // local argmin: 4 independent depth-4 chains + 2-level merge.
            float b0 = INFV, b1 = INFV, b2 = INFV, b3 = INFV;
            int   p0 = 0, p1 = 0, p2 = 0, p3 = 0;
#pragma unroll
            for (int k = 0; k < 4; ++k) {
                bool t0 = minv[k]      < b0;
                b0 = t0 ? minv[k]      : b0;  p0 = t0 ? jpk[k]      : p0;
                bool t1 = minv[k + 4]  < b1;
                b1 = t1 ? minv[k + 4]  : b1;  p1 = t1 ? jpk[k + 4]  : p1;
                bool t2 = minv[k + 8]  < b2;
                b2 = t2 ? minv[k + 8]  : b2;  p2 = t2 ? jpk[k + 8]  : p2;
                bool t3 = minv[k + 12] < b3;
                b3 = t3 ? minv[k + 12] : b3;  p3 = t3 ? jpk[k + 12] : p3;
            }
            bool m01 = b1 < b0;  float ba = m01 ? b1 : b0;  int pa = m01 ? p1 : p0;
            bool m23 = b3 < b2;  float bb = m23 ? b3 : b2;  int pb = m23 ? p3 : p2;
            bool mab = bb < ba;  float bestv = mab ? bb : ba;
            int bestjp = mab ? pb : pa;

            float gmin = wave_min_f32(bestv);
            if (!(gmin < INFV * 0.5f)) break;
            unsigned long long tm = __ballot(bestv == gmin);
            DT = gmin;
            freecol = 0;

            // 1) free-column short-circuit: single ballot (equivalent to
            //    scanning ties lowest-lane-first for a free bestjp)
            {
                unsigned long long tf =
                    __ballot((bestv == gmin) && ((bestjp >> 11) == 0));
                if (tf) {
                    int l = __ffsll((long long)tf) - 1;
                    freecol = __builtin_amdgcn_readlane(bestjp, l) & 0x7FF;
                }
            }
            if (freecol) break;

            // 2) settle all matched ties at gmin
            bool first = true;
            while (tm) {
                int l = __ffsll((long long)tm) - 1;
                tm &= tm - 1;
                int jp = __builtin_amdgcn_readlane(bestjp, l);
                int jj = jp & 0x7FF, rr = jp >> 11;
                Frag F;
                if (CACHED && first && pred != 0 && rr == pred) {
                    F = P;                         // prefetch hit: data resident
                } else {
                    F = issueLoads(rr);            // loads fly during marking
                }
                if (CACHED && first) {
                    // runner-up prefetch for the NEXT round; the wave-min +
                    // ballot here hides under the winner's L2 load latency.
                    float ru = (bestv == gmin) ? INFV : bestv;
                    float rmin = wave_min_f32(ru);
                    pred = 0;
                    if (rmin < INFV * 0.5f) {
                        unsigned long long rb = __ballot(ru == rmin);
                        int rl = __ffsll((long long)rb) - 1;
                        int rjp = __builtin_amdgcn_readlane(bestjp, rl);
                        int prr = rjp >> 11;
                        if (prr != 0) { pred = prr; P = issueLoads(prr); }
                    }
                }
                first = false;
                if (lane == 0) dentry[jj] = gmin;
                int cc = jj - 1, lo = cc >> 4, kk = cc & 15;
                bool mine = (lane == lo);
#pragma unroll
                for (int k = 0; k < NSLOT; ++k)
                    if (k == kk && mine) { minv[k] = NANF; used |= (1u << k); }
                applyFrag(F, jj, gmin);
            }
        }
        if (freecol == 0) continue;

        // deferred dual updates (pre-augment pr)
        if (lane == 0) u_lds[i] += DT;
#pragma unroll
        for (int k = 0; k < NSLOT; ++k) {
            if ((used >> k) & 1u) {
                int j = lane * NSLOT + k + 1;
                float dd = DT - dentry[j];
                v[k] -= dd;
                u_lds[pr[k]] += dd;      // distinct rows: race-free
            }
        }
        __syncthreads();

        // augment along alternating path (register p via readlanes)
        int j0 = freecol;
        int aguard = 0;
        while (j0 != 0) {
            if (++aguard > N + 4) break;
            int cc = j0 - 1;
            int lo = cc >> 4, kk = cc & 15;
            int wloc = way[0];
#pragma unroll
            for (int k = 1; k < NSLOT; ++k) if (k == kk) wloc = way[k];
            int j1 = __builtin_amdgcn_readlane(wloc, lo);
            int np;
            if (j1 == 0) np = i;
            else {
                int c1 = j1 - 1;
                int lo1 = c1 >> 4, kk1 = c1 & 15;
                int ploc = pr[0];
#pragma unroll
                for (int k = 1; k < NSLOT; ++k) if (k == kk1) ploc = pr[k];
                np = __builtin_amdgcn_readlane(ploc, lo1);
            }
            bool mine = (lane == lo);
#pragma unroll
            for (int k = 0; k < NSLOT; ++k)
                if (k == kk) {
                    if (mine) { pr[k] = np; jpk[k] = (np << 11) | j0; }
                }
            if (lane == 0) rowm[np] = j0;
            j0 = j1;
        }
        __syncthreads();
    }

    // ---- total matched cost: exact fp32 from coordinates ----
    float sum = 0.0f;
#pragma unroll
    for (int k = 0; k < NSLOT; ++k) {
        int r = pr[k] > 0 ? pr[k] : 1;
        float4 qq = s1u[r];
        float dx = qq.x - x2[k], dy = qq.y - y2[k], dz = qq.z - z2[k];
        sum += sqrtf(dx * dx + dy * dy + dz * dz);
    }
#pragma unroll
    for (int off = 32; off >= 1; off >>= 1) sum += __shfl_xor(sum, off);
    if (lane == 0) atomicAdd(out, sum * (1.0f / ((float)N * (float)BATCH)));
}

extern "C" void kernel_launch(void* const* d_in, const int* in_sizes, int n_in,
                              void* d_out, int out_size, void* d_ws, size_t ws_size,
                              hipStream_t stream) {
    const float* S1 = (const float*)d_in[0];
    const float* S2 = (const float*)d_in[1];
    float* out = (float*)d_out;

    size_t needD  = (size_t)BATCH * N * N * sizeof(__half);
    size_t vecB   = (size_t)BATCH * N * 4;            // one per-col/per-row array
    size_t needT  = needD + 2 * vecB;                 // V + I            (R8 tier)
    size_t needT2 = needD + 6 * vecB;                 // + Vw,Uw,Cw,Rw    (R13 tier)

    emd_zero_kernel<<<1, 1, 0, stream>>>(out);

    if (ws_size >= needT2) {
        __half* D  = (__half*)d_ws;
        float*  V  = (float*)((char*)d_ws + needD);
        int*    I  = (int*)((char*)V + vecB);
        float*  Vw = (float*)((char*)I + vecB);
        float*  Uw = (float*)((char*)Vw + vecB);
        int*    Cw = (int*)((char*)Uw + vecB);
        int*    Rw = (int*)((char*)Cw + vecB);
        emd_dist_kernel<<<BATCH * N, 256, 0, stream>>>(S1, S2, D);
        emd_colmin_kernel<<<BATCH * 4, 256, 0, stream>>>(D, V, I);
        emd_auction_kernel<<<BATCH, 1024, 0, stream>>>(D, V, I, Vw, Uw, Cw, Rw);
        emd_jv_kernel<true, true><<<BATCH, 64, 0, stream>>>(
            S1, S2, D, Vw, nullptr, Uw, Cw, Rw, out);
    } else if (ws_size >= needT) {
        __half* D = (__half*)d_ws;
        float*  V = (float*)((char*)d_ws + needD);
        int*    I = (int*)((char*)V + vecB);
        emd_dist_kernel<<<BATCH * N, 256, 0, stream>>>(S1, S2, D);
        emd_colmin_kernel<<<BATCH * 4, 256, 0, stream>>>(D, V, I);
        emd_jv_kernel<true, false><<<BATCH, 64, 0, stream>>>(
            S1, S2, D, V, I, nullptr, nullptr, nullptr, out);
    } else {
        emd_jv_kernel<false, false><<<BATCH, 64, 0, stream>>>(
            S1, S2, nullptr, nullptr, nullptr, nullptr, nullptr, nullptr, out);
    }
}